// Round 17
// baseline (312.253 us; speedup 1.0000x reference)
//
#include <hip/hip_runtime.h>
#include <math.h>

#define NCELL 100000
#define NNET  100000
#define NPIN  500000
#define NNN   200000
#define NPAIR 500000
#define NSCAN (4 * NNET)
#define SCAN_BLOCKS ((NSCAN + 1023) / 1024)    // 391
#define PART_SZ ((NNET + 7) / 8)               // 12500

#define GA_BLOCKS 2048   // fused A: every block = 3 atomic-role waves + 1 lin-role wave

typedef __attribute__((ext_vector_type(8))) short short8;
typedef __attribute__((ext_vector_type(4))) float f32x4;
typedef unsigned short u16;
typedef unsigned int u32;
typedef unsigned long long u64;

__device__ __forceinline__ u16 f2bf(float x) {
    union { float f; u32 u; } v; v.f = x;
    u32 r = (v.u + 0x7FFF + ((v.u >> 16) & 1)) >> 16;
    return (u16)r;
}
__device__ __forceinline__ float bf2f(u16 u) {
    union { u32 u; float f; } v; v.u = ((u32)u) << 16; return v.f;
}
__device__ __forceinline__ u32 cvtpk(float lo, float hi) {
    u32 r;
    asm("v_cvt_pk_bf16_f32 %0, %1, %2" : "=v"(r) : "v"(lo), "v"(hi));
    return r;
}
__device__ __forceinline__ u16 f2bf_fast(float v) {
    return (u16)(cvtpk(v, v) & 0xffffu);
}
__device__ __forceinline__ float plo(u32 h) { return bf2f((u16)(h & 0xffff)); }
__device__ __forceinline__ float phi(u32 h) { return bf2f((u16)(h >> 16)); }

__device__ __forceinline__ float softplusf(float x) {
    return fmaxf(x, 0.f) + __logf(1.f + __expf(-fabsf(x)));
}
__device__ __forceinline__ float sspf(float x) {
    return softplusf(x) - 0.69314718055994530942f;
}
__device__ __forceinline__ float ftanh(float x) {
    float xc = fminf(fmaxf(x, -9.f), 9.f);
    float e = __expf(2.f * xc);
    return (e - 1.f) * __builtin_amdgcn_rcpf(e + 1.f);
}

__device__ __forceinline__ short8 load_bfrag(const float* __restrict__ W,
                                             int kt, int nt, int lane) {
    int k0 = kt * 32 + ((lane >> 4) & 3) * 8;
    int c = nt * 16 + (lane & 15);
    short8 f;
#pragma unroll
    for (int j = 0; j < 8; j++) f[j] = (short)f2bf(W[(k0 + j) * 64 + c]);
    return f;
}

// ===== FUSION A (wave-split): waves 0-2 = degrees/rank atomics, wave 3 = input linears =====
__global__ __launch_bounds__(256) void k_fusedA(
    const int* __restrict__ pin_cell, const int* __restrict__ pin_net,
    const int* __restrict__ nn_src, const int* __restrict__ nn_dst,
    u32* __restrict__ cnt,
    u32* __restrict__ rankNp, u32* __restrict__ rankC,
    u32* __restrict__ rankD, u32* __restrict__ rankS,
    const float* __restrict__ cf, const float* __restrict__ nf,
    const float* __restrict__ Wc, const float* __restrict__ bc,
    const float* __restrict__ Wn, const float* __restrict__ bn,
    u16* __restrict__ h_cell, u16* __restrict__ h_net) {
    int tid = threadIdx.x, lane = tid & 63, w = tid >> 6;
    if (w < 3) {
        // atomic role: 6144 waves -> ~393k lanes, near-full outstanding-atomic concurrency
        int slot = blockIdx.x * 3 + w;
        int stride = GA_BLOCKS * 3 * 64;
        for (int i = slot * 64 + lane; i < NPIN; i += stride) {
            rankNp[i] = atomicAdd(&cnt[pin_net[i]], 1u);
            rankC[i]  = atomicAdd(&cnt[NNET + pin_cell[i]], 1u);
        }
        for (int i = slot * 64 + lane; i < NNN; i += stride) {
            rankD[i] = atomicAdd(&cnt[2 * NNET + nn_dst[i]], 1u);
            rankS[i] = atomicAdd(&cnt[3 * NNET + nn_src[i]], 1u);
        }
    } else {
        // lin role: 2048 waves; VALU-bound, hides fully under the atomic wall
        float wc[16], wn[16];
#pragma unroll
        for (int k = 0; k < 16; k++) { wc[k] = Wc[k * 64 + lane]; wn[k] = Wn[k * 64 + lane]; }
        float bC = bc[lane], bN = bn[lane];
        int wave = blockIdx.x, nw = GA_BLOCKS;
        for (int r = wave; r < NCELL; r += nw) {
            const float4* ip = (const float4*)(cf + (size_t)r * 16);
            float4 a = ip[0], bv = ip[1], c = ip[2], d = ip[3];
            float acc = bC;
            acc = fmaf(a.x, wc[0], acc);  acc = fmaf(a.y, wc[1], acc);
            acc = fmaf(a.z, wc[2], acc);  acc = fmaf(a.w, wc[3], acc);
            acc = fmaf(bv.x, wc[4], acc); acc = fmaf(bv.y, wc[5], acc);
            acc = fmaf(bv.z, wc[6], acc); acc = fmaf(bv.w, wc[7], acc);
            acc = fmaf(c.x, wc[8], acc);  acc = fmaf(c.y, wc[9], acc);
            acc = fmaf(c.z, wc[10], acc); acc = fmaf(c.w, wc[11], acc);
            acc = fmaf(d.x, wc[12], acc); acc = fmaf(d.y, wc[13], acc);
            acc = fmaf(d.z, wc[14], acc); acc = fmaf(d.w, wc[15], acc);
            float v = ftanh(acc);
            float vp = __shfl_xor(v, 1, 64);
            if (!(lane & 1))
                *(u32*)(h_cell + (size_t)r * 64 + lane) = cvtpk(v, vp);
        }
        for (int r = wave; r < NNET; r += nw) {
            const float4* ip = (const float4*)(nf + (size_t)r * 16);
            float4 a = ip[0], bv = ip[1], c = ip[2], d = ip[3];
            float acc = bN;
            acc = fmaf(a.x, wn[0], acc);  acc = fmaf(a.y, wn[1], acc);
            acc = fmaf(a.z, wn[2], acc);  acc = fmaf(a.w, wn[3], acc);
            acc = fmaf(bv.x, wn[4], acc); acc = fmaf(bv.y, wn[5], acc);
            acc = fmaf(bv.z, wn[6], acc); acc = fmaf(bv.w, wn[7], acc);
            acc = fmaf(c.x, wn[8], acc);  acc = fmaf(c.y, wn[9], acc);
            acc = fmaf(c.z, wn[10], acc); acc = fmaf(c.w, wn[11], acc);
            acc = fmaf(d.x, wn[12], acc); acc = fmaf(d.y, wn[13], acc);
            acc = fmaf(d.z, wn[14], acc); acc = fmaf(d.w, wn[15], acc);
            float v = ftanh(acc);
            float vp = __shfl_xor(v, 1, 64);
            if (!(lane & 1))
                *(u32*)(h_net + (size_t)r * 64 + lane) = cvtpk(v, vp);
        }
    }
}

// ---------------- scan1 + deg_fin fused ----------------
__global__ __launch_bounds__(256) void k_scan1(const u32* __restrict__ in,
                                               u32* __restrict__ out, u32* __restrict__ bsum,
                                               float* __restrict__ deg) {
    __shared__ u32 sc[256];
    int t = threadIdx.x;
    int base = blockIdx.x * 1024 + t * 4;
    u32 v0 = base + 0 < NSCAN ? in[base + 0] : 0;
    u32 v1 = base + 1 < NSCAN ? in[base + 1] : 0;
    u32 v2 = base + 2 < NSCAN ? in[base + 2] : 0;
    u32 v3 = base + 3 < NSCAN ? in[base + 3] : 0;
    if (base + 0 < NSCAN) deg[base + 0] = rsqrtf((float)max(v0, 1u));
    if (base + 1 < NSCAN) deg[base + 1] = rsqrtf((float)max(v1, 1u));
    if (base + 2 < NSCAN) deg[base + 2] = rsqrtf((float)max(v2, 1u));
    if (base + 3 < NSCAN) deg[base + 3] = rsqrtf((float)max(v3, 1u));
    u32 s = v0 + v1 + v2 + v3;
    sc[t] = s; __syncthreads();
    for (int off = 1; off < 256; off <<= 1) {
        u32 x = (t >= off) ? sc[t - off] : 0; __syncthreads();
        sc[t] += x; __syncthreads();
    }
    u32 excl = sc[t] - s;
    if (base + 0 < NSCAN) out[base + 0] = excl;
    if (base + 1 < NSCAN) out[base + 1] = excl + v0;
    if (base + 2 < NSCAN) out[base + 2] = excl + v0 + v1;
    if (base + 3 < NSCAN) out[base + 3] = excl + v0 + v1 + v2;
    if (t == 255) bsum[blockIdx.x] = sc[255];
}

__global__ __launch_bounds__(512) void k_scan2(u32* __restrict__ bsum) {
    __shared__ u32 sc[512];
    int t = threadIdx.x;
    u32 v = (t < SCAN_BLOCKS) ? bsum[t] : 0;
    sc[t] = v; __syncthreads();
    for (int off = 1; off < 512; off <<= 1) {
        u32 x = (t >= off) ? sc[t - off] : 0; __syncthreads();
        sc[t] += x; __syncthreads();
    }
    if (t < SCAN_BLOCKS) bsum[t] = sc[t] - v;
}

__global__ __launch_bounds__(256) void k_scan3(u32* __restrict__ S, const u32* __restrict__ bsum) {
    int i = blockIdx.x * blockDim.x + threadIdx.x;
    if (i < NSCAN) S[i] = S[i] + bsum[i >> 10];
    if (i == 0) S[NSCAN] = 2u * NPIN + 2u * NNN;
}

// ---------------- CSR placement, atomic-free, XCD-partitioned ----------------
__global__ __launch_bounds__(256) void k_place_part(
    const int* __restrict__ pin_cell, const int* __restrict__ pin_net,
    const int* __restrict__ nn_src, const int* __restrict__ nn_dst,
    const u32* __restrict__ S,
    const u32* __restrict__ rankNp, const u32* __restrict__ rankC,
    const u32* __restrict__ rankD, const u32* __restrict__ rankS,
    u32* __restrict__ colC, u64* __restrict__ colPN,
    u32* __restrict__ colS, u32* __restrict__ colD) {
    int part = blockIdx.x & 7;
    int grp = blockIdx.x >> 3;
    int ngrp = gridDim.x >> 3;
    int lo = part * PART_SZ, hi = lo + PART_SZ;
    int stride = ngrp * 256;
    for (int e = grp * 256 + threadIdx.x; e < NPIN; e += stride) {
        int n = pin_net[e], c = pin_cell[e];
        if (n >= lo && n < hi)
            colC[S[n] + rankNp[e]] = (u32)c;
        if (c >= lo && c < hi)
            colPN[S[NNET + c] + rankC[e] - NPIN] = (u64)(u32)e | ((u64)(u32)n << 32);
    }
    for (int i = grp * 256 + threadIdx.x; i < NNN; i += stride) {
        int s = nn_src[i], d = nn_dst[i];
        if (d >= lo && d < hi)
            colS[S[2 * NNET + d] + rankD[i] - 2u * NPIN] = (u32)s;
        if (s >= lo && s < hi)
            colD[S[3 * NNET + s] + rankS[i] - (2u * NPIN + NNN)] = (u32)d;
    }
}

// ---------------- e-MLP in cell-CSR slot order ----------------
__global__ __launch_bounds__(256, 4) void k_emlp(
    const float* __restrict__ pin_feat, const u64* __restrict__ colPN,
    const float* __restrict__ E1, const float* __restrict__ b1,
    const float* __restrict__ E2, const float* __restrict__ b2,
    u16* __restrict__ etab) {
    __shared__ __align__(16) u16 sm[4][1024];
    int tid = threadIdx.x, lane = tid & 63, w = tid >> 6;
    int l15 = lane & 15, g = (lane >> 4) & 3;
    short8 B1[4];
#pragma unroll
    for (int nt = 0; nt < 4; nt++) {
        short8 f = {0, 0, 0, 0, 0, 0, 0, 0};
        if (lane < 16) {
            int c = nt * 16 + l15;
#pragma unroll
            for (int j = 0; j < 8; j++) f[j] = (short)f2bf(E1[j * 64 + c]);
        }
        B1[nt] = f;
    }
    short8 B2[2][4];
#pragma unroll
    for (int kt = 0; kt < 2; kt++)
#pragma unroll
        for (int nt = 0; nt < 4; nt++) B2[kt][nt] = load_bfrag(E2, kt, nt, lane);
    float bb1[4], bb2[4];
#pragma unroll
    for (int nt = 0; nt < 4; nt++) {
        bb1[nt] = b1[nt * 16 + l15];
        bb2[nt] = b2[nt * 16 + l15];
    }
    int wave = blockIdx.x * 4 + w, nwave = gridDim.x * 4;
    const int ntile = NPIN >> 4;
    f32x4 z = {0.f, 0.f, 0.f, 0.f};
    for (int t = wave; t < ntile; t += nwave) {
        int P = t << 4;
        short8 a1 = {0, 0, 0, 0, 0, 0, 0, 0};
        if (lane < 16) {
            u32 p = (u32)colPN[P + lane];
            const float4* q = (const float4*)(pin_feat + (size_t)p * 8);
            float4 u0 = q[0], u1 = q[1];
            u32 w01 = cvtpk(u0.x, u0.y), w23 = cvtpk(u0.z, u0.w);
            u32 w45 = cvtpk(u1.x, u1.y), w67 = cvtpk(u1.z, u1.w);
            a1[0] = (short)(w01 & 0xffff); a1[1] = (short)(w01 >> 16);
            a1[2] = (short)(w23 & 0xffff); a1[3] = (short)(w23 >> 16);
            a1[4] = (short)(w45 & 0xffff); a1[5] = (short)(w45 >> 16);
            a1[6] = (short)(w67 & 0xffff); a1[7] = (short)(w67 >> 16);
        }
#pragma unroll
        for (int nt = 0; nt < 4; nt++) {
            f32x4 c1 = __builtin_amdgcn_mfma_f32_16x16x32_bf16(a1, B1[nt], z, 0, 0, 0);
#pragma unroll
            for (int r = 0; r < 4; r++) {
                int row = g * 4 + r;
                int col = nt * 16 + l15;
                sm[w][row * 64 + (col ^ ((row & 7) << 3))] = f2bf_fast(sspf(c1[r] + bb1[nt]));
            }
        }
        short8 a2[2];
#pragma unroll
        for (int kt = 0; kt < 2; kt++) {
            int idx = l15 * 64 + ((kt * 32 + g * 8) ^ ((l15 & 7) << 3));
            a2[kt] = *(const short8*)&sm[w][idx];
        }
#pragma unroll
        for (int nt = 0; nt < 4; nt++) {
            f32x4 e = __builtin_amdgcn_mfma_f32_16x16x32_bf16(a2[0], B2[0][nt], z, 0, 0, 0);
            e = __builtin_amdgcn_mfma_f32_16x16x32_bf16(a2[1], B2[1][nt], e, 0, 0, 0);
#pragma unroll
            for (int r = 0; r < 4; r++) {
                float v = sspf(e[r] + bb2[nt]);
                float vp = __shfl_xor(v, 1, 64);
                if (!(lane & 1))
                    *(u32*)(etab + (size_t)(P + g * 4 + r) * 64 + nt * 16 + l15) = cvtpk(v, vp);
            }
        }
    }
}

// ---------------- hv = h_net @ cf_node_w + b ----------------
__global__ __launch_bounds__(256, 4) void k_mm64hv(
    const u16* __restrict__ in, const float* __restrict__ W,
    const float* __restrict__ b, u16* __restrict__ out, int n) {
    int tid = threadIdx.x, lane = tid & 63, w = tid >> 6;
    int l15 = lane & 15, g = (lane >> 4) & 3;
    short8 Bf[2][4];
    float bias[4];
#pragma unroll
    for (int kt = 0; kt < 2; kt++)
#pragma unroll
        for (int nt = 0; nt < 4; nt++) Bf[kt][nt] = load_bfrag(W, kt, nt, lane);
#pragma unroll
    for (int nt = 0; nt < 4; nt++) bias[nt] = b[nt * 16 + l15];
    int wave = blockIdx.x * 4 + w, nwave = gridDim.x * 4;
    int ntile = n >> 4;
    f32x4 z = {0.f, 0.f, 0.f, 0.f};
    for (int t = wave; t < ntile; t += nwave) {
        int R = t << 4;
        const u16* rb = in + (size_t)(R + l15) * 64;
        short8 a0 = *(const short8*)(rb + g * 8);
        short8 a1 = *(const short8*)(rb + 32 + g * 8);
#pragma unroll
        for (int nt = 0; nt < 4; nt++) {
            f32x4 acc = __builtin_amdgcn_mfma_f32_16x16x32_bf16(a0, Bf[0][nt], z, 0, 0, 0);
            acc = __builtin_amdgcn_mfma_f32_16x16x32_bf16(a1, Bf[1][nt], acc, 0, 0, 0);
#pragma unroll
            for (int r = 0; r < 4; r++) {
                float v = acc[r] + bias[nt];
                float vp = __shfl_xor(v, 1, 64);
                if (!(lane & 1))
                    *(u32*)(out + (size_t)(R + g * 4 + r) * 64 + nt * 16 + l15) = cvtpk(v, vp);
            }
        }
    }
}

// ---------------- gather-sum: accP[n] = sum rC[c]*h_cell[c] ----------------
__global__ __launch_bounds__(256) void k_gatherP(
    const u32* __restrict__ S, const u32* __restrict__ colC,
    const u16* __restrict__ h_cell, const float* __restrict__ rCv,
    u16* __restrict__ accP) {
    int l32 = threadIdx.x & 31, off2 = l32 * 2;
    int slot = blockIdx.x * 8 + (threadIdx.x >> 5), ns = gridDim.x * 8;
    for (int n = slot; n < NNET; n += ns) {
        u32 b0 = S[n], b1 = S[n + 1];
        float fa = 0.f, fb = 0.f, ga = 0.f, gb = 0.f;
        u32 k = b0;
        for (; k + 1 < b1; k += 2) {
            u32 c0 = colC[k], c1 = colC[k + 1];
            float r0 = rCv[c0], r1 = rCv[c1];
            u32 h0 = *(const u32*)(h_cell + (size_t)c0 * 64 + off2);
            u32 h1 = *(const u32*)(h_cell + (size_t)c1 * 64 + off2);
            fa = fmaf(plo(h0), r0, fa); fb = fmaf(phi(h0), r0, fb);
            ga = fmaf(plo(h1), r1, ga); gb = fmaf(phi(h1), r1, gb);
        }
        if (k < b1) {
            u32 c0 = colC[k];
            float r0 = rCv[c0];
            u32 h0 = *(const u32*)(h_cell + (size_t)c0 * 64 + off2);
            fa = fmaf(plo(h0), r0, fa); fb = fmaf(phi(h0), r0, fb);
        }
        *(u32*)(accP + (size_t)n * 64 + off2) = cvtpk(fa + ga, fb + gb);
    }
}

// ---------------- gather-sum for both nn relations ----------------
__global__ __launch_bounds__(256) void k_gatherFS(
    const u32* __restrict__ S, const u32* __restrict__ colS, const u32* __restrict__ colD,
    const u16* __restrict__ h_net, const float* __restrict__ rDv, const float* __restrict__ rSv,
    u16* __restrict__ accF, u16* __restrict__ accS) {
    int l32 = threadIdx.x & 31, off2 = l32 * 2;
    int slot = blockIdx.x * 8 + (threadIdx.x >> 5), ns = gridDim.x * 8;
    for (int r = slot; r < 2 * NNET; r += ns) {
        if (r < NNET) {
            int d = r;
            u32 b0 = S[2 * NNET + d] - 2u * NPIN, b1 = S[2 * NNET + d + 1] - 2u * NPIN;
            float fa = 0.f, fb = 0.f, ga = 0.f, gb = 0.f;
            u32 k = b0;
            for (; k + 1 < b1; k += 2) {
                u32 s0 = colS[k], s1 = colS[k + 1];
                float c0 = rSv[s0], c1 = rSv[s1];
                u32 h0 = *(const u32*)(h_net + (size_t)s0 * 64 + off2);
                u32 h1 = *(const u32*)(h_net + (size_t)s1 * 64 + off2);
                fa = fmaf(plo(h0), c0, fa); fb = fmaf(phi(h0), c0, fb);
                ga = fmaf(plo(h1), c1, ga); gb = fmaf(phi(h1), c1, gb);
            }
            if (k < b1) {
                u32 s0 = colS[k];
                float c0 = rSv[s0];
                u32 h0 = *(const u32*)(h_net + (size_t)s0 * 64 + off2);
                fa = fmaf(plo(h0), c0, fa); fb = fmaf(phi(h0), c0, fb);
            }
            *(u32*)(accF + (size_t)d * 64 + off2) = cvtpk(fa + ga, fb + gb);
        } else {
            int s = r - NNET;
            u32 b0 = S[3 * NNET + s] - (2u * NPIN + NNN), b1 = S[3 * NNET + s + 1] - (2u * NPIN + NNN);
            float fa = 0.f, fb = 0.f, ga = 0.f, gb = 0.f;
            u32 k = b0;
            for (; k + 1 < b1; k += 2) {
                u32 d0 = colD[k], d1 = colD[k + 1];
                float c0 = rDv[d0], c1 = rDv[d1];
                u32 h0 = *(const u32*)(h_net + (size_t)d0 * 64 + off2);
                u32 h1 = *(const u32*)(h_net + (size_t)d1 * 64 + off2);
                fa = fmaf(plo(h0), c0, fa); fb = fmaf(phi(h0), c0, fb);
                ga = fmaf(plo(h1), c1, ga); gb = fmaf(phi(h1), c1, gb);
            }
            if (k < b1) {
                u32 d0 = colD[k];
                float c0 = rDv[d0];
                u32 h0 = *(const u32*)(h_net + (size_t)d0 * 64 + off2);
                fa = fmaf(plo(h0), c0, fa); fb = fmaf(phi(h0), c0, fb);
            }
            *(u32*)(accS + (size_t)s * 64 + off2) = cvtpk(fa + ga, fb + gb);
        }
    }
}

// ---------------- gather-sum: acc_cell[c] = sum etab_sorted[k] * hv[net(colPN[k])] ----------------
__global__ __launch_bounds__(256) void k_gatherCell(
    const u32* __restrict__ S, const u64* __restrict__ colPN,
    const u16* __restrict__ etab, const u16* __restrict__ hv, u16* __restrict__ acc) {
    int l32 = threadIdx.x & 31, off2 = l32 * 2;
    int slot = blockIdx.x * 8 + (threadIdx.x >> 5), ns = gridDim.x * 8;
    for (int c = slot; c < NCELL; c += ns) {
        u32 b0 = S[NNET + c] - NPIN, b1 = S[NNET + c + 1] - NPIN;
        float fa = 0.f, fb = 0.f, ga = 0.f, gb = 0.f;
        u32 k = b0;
        for (; k + 1 < b1; k += 2) {
            u32 n0 = (u32)(colPN[k] >> 32), n1 = (u32)(colPN[k + 1] >> 32);
            u32 e0 = *(const u32*)(etab + (size_t)k * 64 + off2);
            u32 e1 = *(const u32*)(etab + (size_t)(k + 1) * 64 + off2);
            u32 h0 = *(const u32*)(hv + (size_t)n0 * 64 + off2);
            u32 h1 = *(const u32*)(hv + (size_t)n1 * 64 + off2);
            fa = fmaf(plo(e0), plo(h0), fa); fb = fmaf(phi(e0), phi(h0), fb);
            ga = fmaf(plo(e1), plo(h1), ga); gb = fmaf(phi(e1), phi(h1), gb);
        }
        if (k < b1) {
            u32 n0 = (u32)(colPN[k] >> 32);
            u32 e0 = *(const u32*)(etab + (size_t)k * 64 + off2);
            u32 h0 = *(const u32*)(hv + (size_t)n0 * 64 + off2);
            fa = fmaf(plo(e0), plo(h0), fa); fb = fmaf(phi(e0), phi(h0), fb);
        }
        *(u32*)(acc + (size_t)c * 64 + off2) = cvtpk(fa + ga, fb + gb);
    }
}

// ---------------- 3-relation combine + row scales + fused ntab dots ----------------
__global__ __launch_bounds__(256, 2) void k_combine3(
    const u16* __restrict__ A0, const float* __restrict__ W0, const float* __restrict__ b0,
    const u16* __restrict__ A1, const float* __restrict__ W1, const float* __restrict__ b1,
    const u16* __restrict__ A2, const float* __restrict__ W2, const float* __restrict__ b2,
    const float* __restrict__ sc0, const float* __restrict__ sc1, const float* __restrict__ sc2,
    const float* __restrict__ ndw, const float* __restrict__ naw,
    const float* __restrict__ pdw, const float* __restrict__ paw,
    float* __restrict__ ntab, int n) {
    int tid = threadIdx.x, lane = tid & 63, w = tid >> 6;
    int l15 = lane & 15, g = (lane >> 4) & 3;
    const float* Ws[3] = {W0, W1, W2};
    const float* bs[3] = {b0, b1, b2};
    const u16* As[3] = {A0, A1, A2};
    short8 Bf[3][2][4];
    float bias[3][4];
#pragma unroll
    for (int rel = 0; rel < 3; rel++) {
#pragma unroll
        for (int kt = 0; kt < 2; kt++)
#pragma unroll
            for (int nt = 0; nt < 4; nt++) Bf[rel][kt][nt] = load_bfrag(Ws[rel], kt, nt, lane);
#pragma unroll
        for (int nt = 0; nt < 4; nt++) bias[rel][nt] = bs[rel][nt * 16 + l15];
    }
    float wt[6][4];
#pragma unroll
    for (int nt = 0; nt < 4; nt++) {
        int c = nt * 16 + l15;
        wt[0][nt] = ndw[c];      wt[1][nt] = naw[c];
        wt[2][nt] = ndw[64 + c]; wt[3][nt] = naw[64 + c];
        wt[4][nt] = pdw[c];      wt[5][nt] = paw[c];
    }
    int wave = blockIdx.x * 4 + w, nwave = gridDim.x * 4;
    int ntile = n >> 4;
    f32x4 z = {0.f, 0.f, 0.f, 0.f};
    for (int t = wave; t < ntile; t += nwave) {
        int R = t << 4;
        int rowA = R + l15;
        float s0a[4], s1a[4], s2a[4];
        *(float4*)s0a = *(const float4*)(sc0 + R + g * 4);
        *(float4*)s1a = *(const float4*)(sc1 + R + g * 4);
        *(float4*)s2a = *(const float4*)(sc2 + R + g * 4);
        f32x4 res[4];
#pragma unroll
        for (int rel = 0; rel < 3; rel++) {
            const u16* rb = As[rel] + (size_t)rowA * 64;
            short8 a0 = *(const short8*)(rb + g * 8);
            short8 a1 = *(const short8*)(rb + 32 + g * 8);
            const float* sa = (rel == 0) ? s0a : (rel == 1) ? s1a : s2a;
#pragma unroll
            for (int nt = 0; nt < 4; nt++) {
                f32x4 acc = __builtin_amdgcn_mfma_f32_16x16x32_bf16(a0, Bf[rel][0][nt], z, 0, 0, 0);
                acc = __builtin_amdgcn_mfma_f32_16x16x32_bf16(a1, Bf[rel][1][nt], acc, 0, 0, 0);
                if (rel == 0) {
#pragma unroll
                    for (int r = 0; r < 4; r++) res[nt][r] = sa[r] * acc[r] + bias[0][nt];
                } else {
#pragma unroll
                    for (int r = 0; r < 4; r++)
                        res[nt][r] = fmaxf(res[nt][r], sa[r] * acc[r] + bias[rel][nt]);
                }
            }
        }
#pragma unroll
        for (int r = 0; r < 4; r++) {
            float a0 = 0.f, a1 = 0.f, a2 = 0.f, a3 = 0.f, a4 = 0.f, a5 = 0.f;
#pragma unroll
            for (int nt = 0; nt < 4; nt++) {
                float v = res[nt][r];
                a0 = fmaf(v, wt[0][nt], a0);
                a1 = fmaf(v, wt[1][nt], a1);
                a2 = fmaf(v, wt[2][nt], a2);
                a3 = fmaf(v, wt[3][nt], a3);
                a4 = fmaf(v, wt[4][nt], a4);
                a5 = fmaf(v, wt[5][nt], a5);
            }
#pragma unroll
            for (int off = 1; off < 16; off <<= 1) {
                a0 += __shfl_xor(a0, off, 64);
                a1 += __shfl_xor(a1, off, 64);
                a2 += __shfl_xor(a2, off, 64);
                a3 += __shfl_xor(a3, off, 64);
                a4 += __shfl_xor(a4, off, 64);
                a5 += __shfl_xor(a5, off, 64);
            }
            if (l15 == 0) {
                float* tp = ntab + (size_t)(R + g * 4 + r) * 8;
                *(float2*)tp = float2{a0, a1};
                *(float2*)(tp + 2) = float2{a2, a3};
                *(float2*)(tp + 4) = float2{a4, a5};
            }
        }
    }
}

// ---------------- cell out-layer: ssp(acc @ W + b) fused with ctab dots ----------------
__global__ __launch_bounds__(256, 3) void k_mm64c(
    const u16* __restrict__ in, const float* __restrict__ W, const float* __restrict__ b,
    const float* __restrict__ pdw, const float* __restrict__ paw,
    float* __restrict__ ctab, int n) {
    int tid = threadIdx.x, lane = tid & 63, w = tid >> 6;
    int l15 = lane & 15, g = (lane >> 4) & 3;
    short8 Bf[2][4];
    float bias[4], wdv[4], wav[4];
#pragma unroll
    for (int kt = 0; kt < 2; kt++)
#pragma unroll
        for (int nt = 0; nt < 4; nt++) Bf[kt][nt] = load_bfrag(W, kt, nt, lane);
#pragma unroll
    for (int nt = 0; nt < 4; nt++) {
        int c = nt * 16 + l15;
        bias[nt] = b[c];
        wdv[nt] = pdw[72 + c];
        wav[nt] = paw[72 + c];
    }
    int wave = blockIdx.x * 4 + w, nwave = gridDim.x * 4;
    int ntile = n >> 4;
    f32x4 z = {0.f, 0.f, 0.f, 0.f};
    for (int t = wave; t < ntile; t += nwave) {
        int R = t << 4;
        const u16* rb = in + (size_t)(R + l15) * 64;
        short8 a0 = *(const short8*)(rb + g * 8);
        short8 a1 = *(const short8*)(rb + 32 + g * 8);
        float sd[4] = {0.f, 0.f, 0.f, 0.f}, sa[4] = {0.f, 0.f, 0.f, 0.f};
#pragma unroll
        for (int nt = 0; nt < 4; nt++) {
            f32x4 acc = __builtin_amdgcn_mfma_f32_16x16x32_bf16(a0, Bf[0][nt], z, 0, 0, 0);
            acc = __builtin_amdgcn_mfma_f32_16x16x32_bf16(a1, Bf[1][nt], acc, 0, 0, 0);
#pragma unroll
            for (int r = 0; r < 4; r++) {
                float v = sspf(acc[r] + bias[nt]);
                sd[r] = fmaf(v, wdv[nt], sd[r]);
                sa[r] = fmaf(v, wav[nt], sa[r]);
            }
        }
#pragma unroll
        for (int r = 0; r < 4; r++) {
            float d = sd[r], a = sa[r];
#pragma unroll
            for (int off = 1; off < 16; off <<= 1) {
                d += __shfl_xor(d, off, 64);
                a += __shfl_xor(a, off, 64);
            }
            if (l15 == 0)
                *(float2*)(ctab + (size_t)(R + g * 4 + r) * 2) = float2{d, a};
        }
    }
}

// ---------------- fused pair + pin readout ----------------
__global__ __launch_bounds__(256) void k_readout(
    const int* __restrict__ pairs,
    const float* __restrict__ pin_feat,
    const int* __restrict__ pin_net, const int* __restrict__ pin_cell,
    const float* __restrict__ ntab, const float* __restrict__ ctab,
    const float* __restrict__ plw, const float* __restrict__ plb,
    const float* __restrict__ pdw, const float* __restrict__ paw,
    const float* __restrict__ nbd, const float* __restrict__ nba,
    const float* __restrict__ pbd, const float* __restrict__ pba,
    float* __restrict__ out) {
    int i = blockIdx.x * blockDim.x + threadIdx.x;
    if (i < NPAIR) {
        int p0 = pairs[2 * i], p1 = pairs[2 * i + 1];
        float2 x0 = *(const float2*)(ntab + (size_t)p0 * 8);
        float2 x1 = *(const float2*)(ntab + (size_t)p1 * 8 + 2);
        out[i] = softplusf(x0.x + x1.x + nbd[0]);
        out[NPAIR + i] = x0.y + x1.y + nba[0];
    } else if (i < NPAIR + NPIN) {
        int p = i - NPAIR;
        int n = pin_net[p], c = pin_cell[p];
        float2 ns = *(const float2*)(ntab + (size_t)n * 8 + 4);
        float2 cs = *(const float2*)(ctab + (size_t)c * 2);
        float pf[8];
        *(float4*)pf = *(const float4*)(pin_feat + (size_t)p * 8);
        *(float4*)(pf + 4) = *(const float4*)(pin_feat + (size_t)p * 8 + 4);
        float sd = ns.x + cs.x + pbd[0];
        float sa = ns.y + cs.y + pba[0];
#pragma unroll
        for (int j = 0; j < 8; j++) {
            float a = plb[j];
#pragma unroll
            for (int k = 0; k < 8; k++) a = fmaf(pf[k], plw[k * 8 + j], a);
            float hp = ftanh(a);
            sd = fmaf(hp, pdw[64 + j], sd);
            sa = fmaf(hp, paw[64 + j], sa);
        }
        out[2 * NPAIR + p] = softplusf(sd);
        out[2 * NPAIR + NPIN + p] = sa;
    }
}

extern "C" void kernel_launch(void* const* d_in, const int* in_sizes, int n_in,
                              void* d_out, int out_size, void* d_ws, size_t ws_size,
                              hipStream_t stream) {
    const float* cell_feat = (const float*)d_in[0];
    const float* net_feat  = (const float*)d_in[1];
    const float* pin_feat  = (const float*)d_in[2];
    const float* cell_lin_w = (const float*)d_in[3];
    const float* cell_lin_b = (const float*)d_in[4];
    const float* net_lin_w  = (const float*)d_in[5];
    const float* net_lin_b  = (const float*)d_in[6];
    const float* pin_lin_w  = (const float*)d_in[7];
    const float* pin_lin_b  = (const float*)d_in[8];
    const float* pins_w   = (const float*)d_in[9];
    const float* pins_b   = (const float*)d_in[10];
    const float* father_w = (const float*)d_in[11];
    const float* father_b = (const float*)d_in[12];
    const float* son_w    = (const float*)d_in[13];
    const float* son_b    = (const float*)d_in[14];
    const float* cf_node_w = (const float*)d_in[15];
    const float* cf_node_b = (const float*)d_in[16];
    const float* cf_e1_w  = (const float*)d_in[17];
    const float* cf_e1_b  = (const float*)d_in[18];
    const float* cf_e2_w  = (const float*)d_in[19];
    const float* cf_e2_b  = (const float*)d_in[20];
    const float* cf_out_w = (const float*)d_in[21];
    const float* cf_out_b = (const float*)d_in[22];
    const float* net_dis_w   = (const float*)d_in[23];
    const float* net_dis_b   = (const float*)d_in[24];
    const float* net_angle_w = (const float*)d_in[25];
    const float* net_angle_b = (const float*)d_in[26];
    const float* pin_dis_w   = (const float*)d_in[27];
    const float* pin_dis_b   = (const float*)d_in[28];
    const float* pin_angle_w = (const float*)d_in[29];
    const float* pin_angle_b = (const float*)d_in[30];
    const int* pin_net = (const int*)d_in[31];
    const int* pin_cell = (const int*)d_in[32];
    const int* nn_src = (const int*)d_in[33];
    const int* nn_dst = (const int*)d_in[34];
    const int* pairs = (const int*)d_in[35];

    u16* ws16 = (u16*)d_ws;
    const size_t SZ = (size_t)NNET * 64;
    u16* h_cell   = ws16;
    u16* acc_cell = ws16;
    u16* h_net    = ws16 + SZ;
    u16* accP     = ws16 + 2 * SZ;
    u16* accF     = ws16 + 3 * SZ;
    u16* accS     = ws16 + 4 * SZ;
    u16* etab     = ws16 + 5 * SZ;
    u16* hv       = ws16 + 10 * SZ;
    u32* tail = (u32*)(ws16 + 11 * SZ);
    u32* cnt    = tail;
    u32* Sarr   = cnt + NSCAN;
    u32* rankNp = Sarr + NSCAN + 2;
    u32* rankC  = rankNp + NPIN;
    u32* rankD  = rankC + NPIN;
    u32* rankS  = rankD + NNN;
    u32* colC   = rankS + NNN;
    u32* colS   = colC + NPIN;
    u32* colD   = colS + NNN;
    u64* colPN  = (u64*)(colD + NNN);
    u32* bsum   = (u32*)(colPN + NPIN);
    float* deg  = (float*)(bsum + 512);
    float* rNp = deg;
    float* rC  = deg + NNET;
    float* rD  = deg + 2 * NNET;
    float* rS  = deg + 3 * NNET;
    float* ntab = deg + NSCAN;
    float* ctab = ntab + (size_t)NNET * 8;

    hipMemsetAsync(cnt, 0, NSCAN * sizeof(u32), stream);

    k_fusedA<<<GA_BLOCKS, 256, 0, stream>>>(
        pin_cell, pin_net, nn_src, nn_dst, cnt, rankNp, rankC, rankD, rankS,
        cell_feat, net_feat, cell_lin_w, cell_lin_b, net_lin_w, net_lin_b,
        h_cell, h_net);

    k_scan1<<<SCAN_BLOCKS, 256, 0, stream>>>(cnt, Sarr, bsum, deg);
    k_scan2<<<1, 512, 0, stream>>>(bsum);
    k_scan3<<<(NSCAN + 255) / 256, 256, 0, stream>>>(Sarr, bsum);
    k_place_part<<<2048, 256, 0, stream>>>(pin_cell, pin_net, nn_src, nn_dst,
                                           Sarr, rankNp, rankC, rankD, rankS,
                                           colC, colPN, colS, colD);

    k_emlp<<<2048, 256, 0, stream>>>(pin_feat, colPN, cf_e1_w, cf_e1_b, cf_e2_w, cf_e2_b, etab);
    k_mm64hv<<<1024, 256, 0, stream>>>(h_net, cf_node_w, cf_node_b, hv, NNET);
    k_gatherP<<<2048, 256, 0, stream>>>(Sarr, colC, h_cell, rC, accP);
    k_gatherFS<<<2048, 256, 0, stream>>>(Sarr, colS, colD, h_net, rD, rS, accF, accS);

    k_combine3<<<512, 256, 0, stream>>>(accP, pins_w, pins_b,
                                        accF, father_w, father_b,
                                        accS, son_w, son_b,
                                        rNp, rD, rS,
                                        net_dis_w, net_angle_w, pin_dis_w, pin_angle_w,
                                        ntab, NNET);

    k_gatherCell<<<2048, 256, 0, stream>>>(Sarr, colPN, etab, hv, acc_cell);

    k_mm64c<<<512, 256, 0, stream>>>(acc_cell, cf_out_w, cf_out_b,
                                     pin_dis_w, pin_angle_w, ctab, NCELL);

    float* out = (float*)d_out;
    k_readout<<<(NPAIR + NPIN + 255) / 256, 256, 0, stream>>>(
        pairs, pin_feat, pin_net, pin_cell, ntab, ctab,
        pin_lin_w, pin_lin_b, pin_dis_w, pin_angle_w,
        net_dis_b, net_angle_b, pin_dis_b, pin_angle_b, out);
}

// Round 18
// 308.443 us; speedup vs baseline: 1.0124x; 1.0124x over previous
//
#include <hip/hip_runtime.h>
#include <math.h>

#define NCELL 100000
#define NNET  100000
#define NPIN  500000
#define NNN   200000
#define NPAIR 500000
#define NSCAN (4 * NNET)
#define SCAN_BLOCKS ((NSCAN + 1023) / 1024)    // 391
#define PART_SZ ((NNET + 7) / 8)               // 12500

typedef __attribute__((ext_vector_type(8))) short short8;
typedef __attribute__((ext_vector_type(4))) float f32x4;
typedef unsigned short u16;
typedef unsigned int u32;
typedef unsigned long long u64;

__device__ __forceinline__ u16 f2bf(float x) {
    union { float f; u32 u; } v; v.f = x;
    u32 r = (v.u + 0x7FFF + ((v.u >> 16) & 1)) >> 16;
    return (u16)r;
}
__device__ __forceinline__ float bf2f(u16 u) {
    union { u32 u; float f; } v; v.u = ((u32)u) << 16; return v.f;
}
__device__ __forceinline__ u32 cvtpk(float lo, float hi) {
    u32 r;
    asm("v_cvt_pk_bf16_f32 %0, %1, %2" : "=v"(r) : "v"(lo), "v"(hi));
    return r;
}
__device__ __forceinline__ u16 f2bf_fast(float v) {
    return (u16)(cvtpk(v, v) & 0xffffu);
}
__device__ __forceinline__ float plo(u32 h) { return bf2f((u16)(h & 0xffff)); }
__device__ __forceinline__ float phi(u32 h) { return bf2f((u16)(h >> 16)); }

__device__ __forceinline__ float softplusf(float x) {
    return fmaxf(x, 0.f) + __logf(1.f + __expf(-fabsf(x)));
}
__device__ __forceinline__ float sspf(float x) {
    return softplusf(x) - 0.69314718055994530942f;
}
__device__ __forceinline__ float ftanh(float x) {
    float xc = fminf(fmaxf(x, -9.f), 9.f);
    float e = __expf(2.f * xc);
    return (e - 1.f) * __builtin_amdgcn_rcpf(e + 1.f);
}

__device__ __forceinline__ short8 load_bfrag(const float* __restrict__ W,
                                             int kt, int nt, int lane) {
    int k0 = kt * 32 + ((lane >> 4) & 3) * 8;
    int c = nt * 16 + (lane & 15);
    short8 f;
#pragma unroll
    for (int j = 0; j < 8; j++) f[j] = (short)f2bf(W[(k0 + j) * 64 + c]);
    return f;
}

// ---------------- degrees + rank capture (full grid, 1 edge/thread) ----------------
__global__ void k_degrees(const int* __restrict__ pin_cell, const int* __restrict__ pin_net,
                          const int* __restrict__ nn_src, const int* __restrict__ nn_dst,
                          u32* __restrict__ cnt,
                          u32* __restrict__ rankNp, u32* __restrict__ rankC,
                          u32* __restrict__ rankD, u32* __restrict__ rankS) {
    int i = blockIdx.x * blockDim.x + threadIdx.x;
    if (i < NPIN) {
        rankNp[i] = atomicAdd(&cnt[pin_net[i]], 1u);
        rankC[i]  = atomicAdd(&cnt[NNET + pin_cell[i]], 1u);
    }
    if (i < NNN) {
        rankD[i] = atomicAdd(&cnt[2 * NNET + nn_dst[i]], 1u);
        rankS[i] = atomicAdd(&cnt[3 * NNET + nn_src[i]], 1u);
    }
}

// ---------------- input linears: cells (unscaled) + nets, bf16 out ----------------
__global__ __launch_bounds__(256) void k_lin16_all(
    const float* __restrict__ cf, const float* __restrict__ nf,
    const float* __restrict__ Wc, const float* __restrict__ bc,
    const float* __restrict__ Wn, const float* __restrict__ bn,
    u16* __restrict__ h_cell, u16* __restrict__ h_net) {
    int tid = threadIdx.x, lane = tid & 63, w = tid >> 6;
    float wc[16], wn[16];
#pragma unroll
    for (int k = 0; k < 16; k++) { wc[k] = Wc[k * 64 + lane]; wn[k] = Wn[k * 64 + lane]; }
    float bC = bc[lane], bN = bn[lane];
    int wave = blockIdx.x * 4 + w, nw = gridDim.x * 4;
    for (int r = wave; r < NCELL; r += nw) {
        const float4* ip = (const float4*)(cf + (size_t)r * 16);
        float4 a = ip[0], bv = ip[1], c = ip[2], d = ip[3];
        float acc = bC;
        acc = fmaf(a.x, wc[0], acc);  acc = fmaf(a.y, wc[1], acc);
        acc = fmaf(a.z, wc[2], acc);  acc = fmaf(a.w, wc[3], acc);
        acc = fmaf(bv.x, wc[4], acc); acc = fmaf(bv.y, wc[5], acc);
        acc = fmaf(bv.z, wc[6], acc); acc = fmaf(bv.w, wc[7], acc);
        acc = fmaf(c.x, wc[8], acc);  acc = fmaf(c.y, wc[9], acc);
        acc = fmaf(c.z, wc[10], acc); acc = fmaf(c.w, wc[11], acc);
        acc = fmaf(d.x, wc[12], acc); acc = fmaf(d.y, wc[13], acc);
        acc = fmaf(d.z, wc[14], acc); acc = fmaf(d.w, wc[15], acc);
        float v = ftanh(acc);
        float vp = __shfl_xor(v, 1, 64);
        if (!(lane & 1))
            *(u32*)(h_cell + (size_t)r * 64 + lane) = cvtpk(v, vp);
    }
    for (int r = wave; r < NNET; r += nw) {
        const float4* ip = (const float4*)(nf + (size_t)r * 16);
        float4 a = ip[0], bv = ip[1], c = ip[2], d = ip[3];
        float acc = bN;
        acc = fmaf(a.x, wn[0], acc);  acc = fmaf(a.y, wn[1], acc);
        acc = fmaf(a.z, wn[2], acc);  acc = fmaf(a.w, wn[3], acc);
        acc = fmaf(bv.x, wn[4], acc); acc = fmaf(bv.y, wn[5], acc);
        acc = fmaf(bv.z, wn[6], acc); acc = fmaf(bv.w, wn[7], acc);
        acc = fmaf(c.x, wn[8], acc);  acc = fmaf(c.y, wn[9], acc);
        acc = fmaf(c.z, wn[10], acc); acc = fmaf(c.w, wn[11], acc);
        acc = fmaf(d.x, wn[12], acc); acc = fmaf(d.y, wn[13], acc);
        acc = fmaf(d.z, wn[14], acc); acc = fmaf(d.w, wn[15], acc);
        float v = ftanh(acc);
        float vp = __shfl_xor(v, 1, 64);
        if (!(lane & 1))
            *(u32*)(h_net + (size_t)r * 64 + lane) = cvtpk(v, vp);
    }
}

// ---------------- scan1 + deg_fin fused ----------------
__global__ __launch_bounds__(256) void k_scan1(const u32* __restrict__ in,
                                               u32* __restrict__ out, u32* __restrict__ bsum,
                                               float* __restrict__ deg) {
    __shared__ u32 sc[256];
    int t = threadIdx.x;
    int base = blockIdx.x * 1024 + t * 4;
    u32 v0 = base + 0 < NSCAN ? in[base + 0] : 0;
    u32 v1 = base + 1 < NSCAN ? in[base + 1] : 0;
    u32 v2 = base + 2 < NSCAN ? in[base + 2] : 0;
    u32 v3 = base + 3 < NSCAN ? in[base + 3] : 0;
    if (base + 0 < NSCAN) deg[base + 0] = rsqrtf((float)max(v0, 1u));
    if (base + 1 < NSCAN) deg[base + 1] = rsqrtf((float)max(v1, 1u));
    if (base + 2 < NSCAN) deg[base + 2] = rsqrtf((float)max(v2, 1u));
    if (base + 3 < NSCAN) deg[base + 3] = rsqrtf((float)max(v3, 1u));
    u32 s = v0 + v1 + v2 + v3;
    sc[t] = s; __syncthreads();
    for (int off = 1; off < 256; off <<= 1) {
        u32 x = (t >= off) ? sc[t - off] : 0; __syncthreads();
        sc[t] += x; __syncthreads();
    }
    u32 excl = sc[t] - s;
    if (base + 0 < NSCAN) out[base + 0] = excl;
    if (base + 1 < NSCAN) out[base + 1] = excl + v0;
    if (base + 2 < NSCAN) out[base + 2] = excl + v0 + v1;
    if (base + 3 < NSCAN) out[base + 3] = excl + v0 + v1 + v2;
    if (t == 255) bsum[blockIdx.x] = sc[255];
}

__global__ __launch_bounds__(512) void k_scan2(u32* __restrict__ bsum) {
    __shared__ u32 sc[512];
    int t = threadIdx.x;
    u32 v = (t < SCAN_BLOCKS) ? bsum[t] : 0;
    sc[t] = v; __syncthreads();
    for (int off = 1; off < 512; off <<= 1) {
        u32 x = (t >= off) ? sc[t - off] : 0; __syncthreads();
        sc[t] += x; __syncthreads();
    }
    if (t < SCAN_BLOCKS) bsum[t] = sc[t] - v;
}

__global__ __launch_bounds__(256) void k_scan3(u32* __restrict__ S, const u32* __restrict__ bsum) {
    int i = blockIdx.x * blockDim.x + threadIdx.x;
    if (i < NSCAN) S[i] = S[i] + bsum[i >> 10];
    if (i == 0) S[NSCAN] = 2u * NPIN + 2u * NNN;
}

// ---------------- CSR placement, atomic-free, XCD-partitioned ----------------
__global__ __launch_bounds__(256) void k_place_part(
    const int* __restrict__ pin_cell, const int* __restrict__ pin_net,
    const int* __restrict__ nn_src, const int* __restrict__ nn_dst,
    const u32* __restrict__ S,
    const u32* __restrict__ rankNp, const u32* __restrict__ rankC,
    const u32* __restrict__ rankD, const u32* __restrict__ rankS,
    u32* __restrict__ colC, u64* __restrict__ colPN,
    u32* __restrict__ colS, u32* __restrict__ colD) {
    int part = blockIdx.x & 7;
    int grp = blockIdx.x >> 3;
    int ngrp = gridDim.x >> 3;
    int lo = part * PART_SZ, hi = lo + PART_SZ;
    int stride = ngrp * 256;
    for (int e = grp * 256 + threadIdx.x; e < NPIN; e += stride) {
        int n = pin_net[e], c = pin_cell[e];
        if (n >= lo && n < hi)
            colC[S[n] + rankNp[e]] = (u32)c;
        if (c >= lo && c < hi)
            colPN[S[NNET + c] + rankC[e] - NPIN] = (u64)(u32)e | ((u64)(u32)n << 32);
    }
    for (int i = grp * 256 + threadIdx.x; i < NNN; i += stride) {
        int s = nn_src[i], d = nn_dst[i];
        if (d >= lo && d < hi)
            colS[S[2 * NNET + d] + rankD[i] - 2u * NPIN] = (u32)s;
        if (s >= lo && s < hi)
            colD[S[3 * NNET + s] + rankS[i] - (2u * NPIN + NNN)] = (u32)d;
    }
}

// ---------------- e-MLP in cell-CSR slot order ----------------
__global__ __launch_bounds__(256, 4) void k_emlp(
    const float* __restrict__ pin_feat, const u64* __restrict__ colPN,
    const float* __restrict__ E1, const float* __restrict__ b1,
    const float* __restrict__ E2, const float* __restrict__ b2,
    u16* __restrict__ etab) {
    __shared__ __align__(16) u16 sm[4][1024];
    int tid = threadIdx.x, lane = tid & 63, w = tid >> 6;
    int l15 = lane & 15, g = (lane >> 4) & 3;
    short8 B1[4];
#pragma unroll
    for (int nt = 0; nt < 4; nt++) {
        short8 f = {0, 0, 0, 0, 0, 0, 0, 0};
        if (lane < 16) {
            int c = nt * 16 + l15;
#pragma unroll
            for (int j = 0; j < 8; j++) f[j] = (short)f2bf(E1[j * 64 + c]);
        }
        B1[nt] = f;
    }
    short8 B2[2][4];
#pragma unroll
    for (int kt = 0; kt < 2; kt++)
#pragma unroll
        for (int nt = 0; nt < 4; nt++) B2[kt][nt] = load_bfrag(E2, kt, nt, lane);
    float bb1[4], bb2[4];
#pragma unroll
    for (int nt = 0; nt < 4; nt++) {
        bb1[nt] = b1[nt * 16 + l15];
        bb2[nt] = b2[nt * 16 + l15];
    }
    int wave = blockIdx.x * 4 + w, nwave = gridDim.x * 4;
    const int ntile = NPIN >> 4;
    f32x4 z = {0.f, 0.f, 0.f, 0.f};
    for (int t = wave; t < ntile; t += nwave) {
        int P = t << 4;
        short8 a1 = {0, 0, 0, 0, 0, 0, 0, 0};
        if (lane < 16) {
            u32 p = (u32)colPN[P + lane];
            const float4* q = (const float4*)(pin_feat + (size_t)p * 8);
            float4 u0 = q[0], u1 = q[1];
            u32 w01 = cvtpk(u0.x, u0.y), w23 = cvtpk(u0.z, u0.w);
            u32 w45 = cvtpk(u1.x, u1.y), w67 = cvtpk(u1.z, u1.w);
            a1[0] = (short)(w01 & 0xffff); a1[1] = (short)(w01 >> 16);
            a1[2] = (short)(w23 & 0xffff); a1[3] = (short)(w23 >> 16);
            a1[4] = (short)(w45 & 0xffff); a1[5] = (short)(w45 >> 16);
            a1[6] = (short)(w67 & 0xffff); a1[7] = (short)(w67 >> 16);
        }
#pragma unroll
        for (int nt = 0; nt < 4; nt++) {
            f32x4 c1 = __builtin_amdgcn_mfma_f32_16x16x32_bf16(a1, B1[nt], z, 0, 0, 0);
#pragma unroll
            for (int r = 0; r < 4; r++) {
                int row = g * 4 + r;
                int col = nt * 16 + l15;
                sm[w][row * 64 + (col ^ ((row & 7) << 3))] = f2bf_fast(sspf(c1[r] + bb1[nt]));
            }
        }
        short8 a2[2];
#pragma unroll
        for (int kt = 0; kt < 2; kt++) {
            int idx = l15 * 64 + ((kt * 32 + g * 8) ^ ((l15 & 7) << 3));
            a2[kt] = *(const short8*)&sm[w][idx];
        }
#pragma unroll
        for (int nt = 0; nt < 4; nt++) {
            f32x4 e = __builtin_amdgcn_mfma_f32_16x16x32_bf16(a2[0], B2[0][nt], z, 0, 0, 0);
            e = __builtin_amdgcn_mfma_f32_16x16x32_bf16(a2[1], B2[1][nt], e, 0, 0, 0);
#pragma unroll
            for (int r = 0; r < 4; r++) {
                float v = sspf(e[r] + bb2[nt]);
                float vp = __shfl_xor(v, 1, 64);
                if (!(lane & 1))
                    *(u32*)(etab + (size_t)(P + g * 4 + r) * 64 + nt * 16 + l15) = cvtpk(v, vp);
            }
        }
    }
}

// ---------------- hv = h_net @ cf_node_w + b ----------------
__global__ __launch_bounds__(256, 4) void k_mm64hv(
    const u16* __restrict__ in, const float* __restrict__ W,
    const float* __restrict__ b, u16* __restrict__ out, int n) {
    int tid = threadIdx.x, lane = tid & 63, w = tid >> 6;
    int l15 = lane & 15, g = (lane >> 4) & 3;
    short8 Bf[2][4];
    float bias[4];
#pragma unroll
    for (int kt = 0; kt < 2; kt++)
#pragma unroll
        for (int nt = 0; nt < 4; nt++) Bf[kt][nt] = load_bfrag(W, kt, nt, lane);
#pragma unroll
    for (int nt = 0; nt < 4; nt++) bias[nt] = b[nt * 16 + l15];
    int wave = blockIdx.x * 4 + w, nwave = gridDim.x * 4;
    int ntile = n >> 4;
    f32x4 z = {0.f, 0.f, 0.f, 0.f};
    for (int t = wave; t < ntile; t += nwave) {
        int R = t << 4;
        const u16* rb = in + (size_t)(R + l15) * 64;
        short8 a0 = *(const short8*)(rb + g * 8);
        short8 a1 = *(const short8*)(rb + 32 + g * 8);
#pragma unroll
        for (int nt = 0; nt < 4; nt++) {
            f32x4 acc = __builtin_amdgcn_mfma_f32_16x16x32_bf16(a0, Bf[0][nt], z, 0, 0, 0);
            acc = __builtin_amdgcn_mfma_f32_16x16x32_bf16(a1, Bf[1][nt], acc, 0, 0, 0);
#pragma unroll
            for (int r = 0; r < 4; r++) {
                float v = acc[r] + bias[nt];
                float vp = __shfl_xor(v, 1, 64);
                if (!(lane & 1))
                    *(u32*)(out + (size_t)(R + g * 4 + r) * 64 + nt * 16 + l15) = cvtpk(v, vp);
            }
        }
    }
}

// ---------------- gather-sum: accP[n] = sum rC[c]*h_cell[c] ----------------
__global__ __launch_bounds__(256) void k_gatherP(
    const u32* __restrict__ S, const u32* __restrict__ colC,
    const u16* __restrict__ h_cell, const float* __restrict__ rCv,
    u16* __restrict__ accP) {
    int l32 = threadIdx.x & 31, off2 = l32 * 2;
    int slot = blockIdx.x * 8 + (threadIdx.x >> 5), ns = gridDim.x * 8;
    for (int n = slot; n < NNET; n += ns) {
        u32 b0 = S[n], b1 = S[n + 1];
        float fa = 0.f, fb = 0.f, ga = 0.f, gb = 0.f;
        u32 k = b0;
        for (; k + 1 < b1; k += 2) {
            u32 c0 = colC[k], c1 = colC[k + 1];
            float r0 = rCv[c0], r1 = rCv[c1];
            u32 h0 = *(const u32*)(h_cell + (size_t)c0 * 64 + off2);
            u32 h1 = *(const u32*)(h_cell + (size_t)c1 * 64 + off2);
            fa = fmaf(plo(h0), r0, fa); fb = fmaf(phi(h0), r0, fb);
            ga = fmaf(plo(h1), r1, ga); gb = fmaf(phi(h1), r1, gb);
        }
        if (k < b1) {
            u32 c0 = colC[k];
            float r0 = rCv[c0];
            u32 h0 = *(const u32*)(h_cell + (size_t)c0 * 64 + off2);
            fa = fmaf(plo(h0), r0, fa); fb = fmaf(phi(h0), r0, fb);
        }
        *(u32*)(accP + (size_t)n * 64 + off2) = cvtpk(fa + ga, fb + gb);
    }
}

// ---------------- gather-sum for both nn relations ----------------
__global__ __launch_bounds__(256) void k_gatherFS(
    const u32* __restrict__ S, const u32* __restrict__ colS, const u32* __restrict__ colD,
    const u16* __restrict__ h_net, const float* __restrict__ rDv, const float* __restrict__ rSv,
    u16* __restrict__ accF, u16* __restrict__ accS) {
    int l32 = threadIdx.x & 31, off2 = l32 * 2;
    int slot = blockIdx.x * 8 + (threadIdx.x >> 5), ns = gridDim.x * 8;
    for (int r = slot; r < 2 * NNET; r += ns) {
        if (r < NNET) {
            int d = r;
            u32 b0 = S[2 * NNET + d] - 2u * NPIN, b1 = S[2 * NNET + d + 1] - 2u * NPIN;
            float fa = 0.f, fb = 0.f, ga = 0.f, gb = 0.f;
            u32 k = b0;
            for (; k + 1 < b1; k += 2) {
                u32 s0 = colS[k], s1 = colS[k + 1];
                float c0 = rSv[s0], c1 = rSv[s1];
                u32 h0 = *(const u32*)(h_net + (size_t)s0 * 64 + off2);
                u32 h1 = *(const u32*)(h_net + (size_t)s1 * 64 + off2);
                fa = fmaf(plo(h0), c0, fa); fb = fmaf(phi(h0), c0, fb);
                ga = fmaf(plo(h1), c1, ga); gb = fmaf(phi(h1), c1, gb);
            }
            if (k < b1) {
                u32 s0 = colS[k];
                float c0 = rSv[s0];
                u32 h0 = *(const u32*)(h_net + (size_t)s0 * 64 + off2);
                fa = fmaf(plo(h0), c0, fa); fb = fmaf(phi(h0), c0, fb);
            }
            *(u32*)(accF + (size_t)d * 64 + off2) = cvtpk(fa + ga, fb + gb);
        } else {
            int s = r - NNET;
            u32 b0 = S[3 * NNET + s] - (2u * NPIN + NNN), b1 = S[3 * NNET + s + 1] - (2u * NPIN + NNN);
            float fa = 0.f, fb = 0.f, ga = 0.f, gb = 0.f;
            u32 k = b0;
            for (; k + 1 < b1; k += 2) {
                u32 d0 = colD[k], d1 = colD[k + 1];
                float c0 = rDv[d0], c1 = rDv[d1];
                u32 h0 = *(const u32*)(h_net + (size_t)d0 * 64 + off2);
                u32 h1 = *(const u32*)(h_net + (size_t)d1 * 64 + off2);
                fa = fmaf(plo(h0), c0, fa); fb = fmaf(phi(h0), c0, fb);
                ga = fmaf(plo(h1), c1, ga); gb = fmaf(phi(h1), c1, gb);
            }
            if (k < b1) {
                u32 d0 = colD[k];
                float c0 = rDv[d0];
                u32 h0 = *(const u32*)(h_net + (size_t)d0 * 64 + off2);
                fa = fmaf(plo(h0), c0, fa); fb = fmaf(phi(h0), c0, fb);
            }
            *(u32*)(accS + (size_t)s * 64 + off2) = cvtpk(fa + ga, fb + gb);
        }
    }
}

// ---------------- gather-sum: acc_cell[c] = sum etab_sorted[k] * hv[net(colPN[k])] ----------------
__global__ __launch_bounds__(256) void k_gatherCell(
    const u32* __restrict__ S, const u64* __restrict__ colPN,
    const u16* __restrict__ etab, const u16* __restrict__ hv, u16* __restrict__ acc) {
    int l32 = threadIdx.x & 31, off2 = l32 * 2;
    int slot = blockIdx.x * 8 + (threadIdx.x >> 5), ns = gridDim.x * 8;
    for (int c = slot; c < NCELL; c += ns) {
        u32 b0 = S[NNET + c] - NPIN, b1 = S[NNET + c + 1] - NPIN;
        float fa = 0.f, fb = 0.f, ga = 0.f, gb = 0.f;
        u32 k = b0;
        for (; k + 1 < b1; k += 2) {
            u32 n0 = (u32)(colPN[k] >> 32), n1 = (u32)(colPN[k + 1] >> 32);
            u32 e0 = *(const u32*)(etab + (size_t)k * 64 + off2);
            u32 e1 = *(const u32*)(etab + (size_t)(k + 1) * 64 + off2);
            u32 h0 = *(const u32*)(hv + (size_t)n0 * 64 + off2);
            u32 h1 = *(const u32*)(hv + (size_t)n1 * 64 + off2);
            fa = fmaf(plo(e0), plo(h0), fa); fb = fmaf(phi(e0), phi(h0), fb);
            ga = fmaf(plo(e1), plo(h1), ga); gb = fmaf(phi(e1), phi(h1), gb);
        }
        if (k < b1) {
            u32 n0 = (u32)(colPN[k] >> 32);
            u32 e0 = *(const u32*)(etab + (size_t)k * 64 + off2);
            u32 h0 = *(const u32*)(hv + (size_t)n0 * 64 + off2);
            fa = fmaf(plo(e0), plo(h0), fa); fb = fmaf(phi(e0), phi(h0), fb);
        }
        *(u32*)(acc + (size_t)c * 64 + off2) = cvtpk(fa + ga, fb + gb);
    }
}

// ---------------- 3-relation combine + row scales + fused ntab dots ----------------
__global__ __launch_bounds__(256, 2) void k_combine3(
    const u16* __restrict__ A0, const float* __restrict__ W0, const float* __restrict__ b0,
    const u16* __restrict__ A1, const float* __restrict__ W1, const float* __restrict__ b1,
    const u16* __restrict__ A2, const float* __restrict__ W2, const float* __restrict__ b2,
    const float* __restrict__ sc0, const float* __restrict__ sc1, const float* __restrict__ sc2,
    const float* __restrict__ ndw, const float* __restrict__ naw,
    const float* __restrict__ pdw, const float* __restrict__ paw,
    float* __restrict__ ntab, int n) {
    int tid = threadIdx.x, lane = tid & 63, w = tid >> 6;
    int l15 = lane & 15, g = (lane >> 4) & 3;
    const float* Ws[3] = {W0, W1, W2};
    const float* bs[3] = {b0, b1, b2};
    const u16* As[3] = {A0, A1, A2};
    short8 Bf[3][2][4];
    float bias[3][4];
#pragma unroll
    for (int rel = 0; rel < 3; rel++) {
#pragma unroll
        for (int kt = 0; kt < 2; kt++)
#pragma unroll
            for (int nt = 0; nt < 4; nt++) Bf[rel][kt][nt] = load_bfrag(Ws[rel], kt, nt, lane);
#pragma unroll
        for (int nt = 0; nt < 4; nt++) bias[rel][nt] = bs[rel][nt * 16 + l15];
    }
    float wt[6][4];
#pragma unroll
    for (int nt = 0; nt < 4; nt++) {
        int c = nt * 16 + l15;
        wt[0][nt] = ndw[c];      wt[1][nt] = naw[c];
        wt[2][nt] = ndw[64 + c]; wt[3][nt] = naw[64 + c];
        wt[4][nt] = pdw[c];      wt[5][nt] = paw[c];
    }
    int wave = blockIdx.x * 4 + w, nwave = gridDim.x * 4;
    int ntile = n >> 4;
    f32x4 z = {0.f, 0.f, 0.f, 0.f};
    for (int t = wave; t < ntile; t += nwave) {
        int R = t << 4;
        int rowA = R + l15;
        float s0a[4], s1a[4], s2a[4];
        *(float4*)s0a = *(const float4*)(sc0 + R + g * 4);
        *(float4*)s1a = *(const float4*)(sc1 + R + g * 4);
        *(float4*)s2a = *(const float4*)(sc2 + R + g * 4);
        f32x4 res[4];
#pragma unroll
        for (int rel = 0; rel < 3; rel++) {
            const u16* rb = As[rel] + (size_t)rowA * 64;
            short8 a0 = *(const short8*)(rb + g * 8);
            short8 a1 = *(const short8*)(rb + 32 + g * 8);
            const float* sa = (rel == 0) ? s0a : (rel == 1) ? s1a : s2a;
#pragma unroll
            for (int nt = 0; nt < 4; nt++) {
                f32x4 acc = __builtin_amdgcn_mfma_f32_16x16x32_bf16(a0, Bf[rel][0][nt], z, 0, 0, 0);
                acc = __builtin_amdgcn_mfma_f32_16x16x32_bf16(a1, Bf[rel][1][nt], acc, 0, 0, 0);
                if (rel == 0) {
#pragma unroll
                    for (int r = 0; r < 4; r++) res[nt][r] = sa[r] * acc[r] + bias[0][nt];
                } else {
#pragma unroll
                    for (int r = 0; r < 4; r++)
                        res[nt][r] = fmaxf(res[nt][r], sa[r] * acc[r] + bias[rel][nt]);
                }
            }
        }
#pragma unroll
        for (int r = 0; r < 4; r++) {
            float a0 = 0.f, a1 = 0.f, a2 = 0.f, a3 = 0.f, a4 = 0.f, a5 = 0.f;
#pragma unroll
            for (int nt = 0; nt < 4; nt++) {
                float v = res[nt][r];
                a0 = fmaf(v, wt[0][nt], a0);
                a1 = fmaf(v, wt[1][nt], a1);
                a2 = fmaf(v, wt[2][nt], a2);
                a3 = fmaf(v, wt[3][nt], a3);
                a4 = fmaf(v, wt[4][nt], a4);
                a5 = fmaf(v, wt[5][nt], a5);
            }
#pragma unroll
            for (int off = 1; off < 16; off <<= 1) {
                a0 += __shfl_xor(a0, off, 64);
                a1 += __shfl_xor(a1, off, 64);
                a2 += __shfl_xor(a2, off, 64);
                a3 += __shfl_xor(a3, off, 64);
                a4 += __shfl_xor(a4, off, 64);
                a5 += __shfl_xor(a5, off, 64);
            }
            if (l15 == 0) {
                float* tp = ntab + (size_t)(R + g * 4 + r) * 8;
                *(float2*)tp = float2{a0, a1};
                *(float2*)(tp + 2) = float2{a2, a3};
                *(float2*)(tp + 4) = float2{a4, a5};
            }
        }
    }
}

// ---------------- cell out-layer: ssp(acc @ W + b) fused with ctab dots ----------------
__global__ __launch_bounds__(256, 3) void k_mm64c(
    const u16* __restrict__ in, const float* __restrict__ W, const float* __restrict__ b,
    const float* __restrict__ pdw, const float* __restrict__ paw,
    float* __restrict__ ctab, int n) {
    int tid = threadIdx.x, lane = tid & 63, w = tid >> 6;
    int l15 = lane & 15, g = (lane >> 4) & 3;
    short8 Bf[2][4];
    float bias[4], wdv[4], wav[4];
#pragma unroll
    for (int kt = 0; kt < 2; kt++)
#pragma unroll
        for (int nt = 0; nt < 4; nt++) Bf[kt][nt] = load_bfrag(W, kt, nt, lane);
#pragma unroll
    for (int nt = 0; nt < 4; nt++) {
        int c = nt * 16 + l15;
        bias[nt] = b[c];
        wdv[nt] = pdw[72 + c];
        wav[nt] = paw[72 + c];
    }
    int wave = blockIdx.x * 4 + w, nwave = gridDim.x * 4;
    int ntile = n >> 4;
    f32x4 z = {0.f, 0.f, 0.f, 0.f};
    for (int t = wave; t < ntile; t += nwave) {
        int R = t << 4;
        const u16* rb = in + (size_t)(R + l15) * 64;
        short8 a0 = *(const short8*)(rb + g * 8);
        short8 a1 = *(const short8*)(rb + 32 + g * 8);
        float sd[4] = {0.f, 0.f, 0.f, 0.f}, sa[4] = {0.f, 0.f, 0.f, 0.f};
#pragma unroll
        for (int nt = 0; nt < 4; nt++) {
            f32x4 acc = __builtin_amdgcn_mfma_f32_16x16x32_bf16(a0, Bf[0][nt], z, 0, 0, 0);
            acc = __builtin_amdgcn_mfma_f32_16x16x32_bf16(a1, Bf[1][nt], acc, 0, 0, 0);
#pragma unroll
            for (int r = 0; r < 4; r++) {
                float v = sspf(acc[r] + bias[nt]);
                sd[r] = fmaf(v, wdv[nt], sd[r]);
                sa[r] = fmaf(v, wav[nt], sa[r]);
            }
        }
#pragma unroll
        for (int r = 0; r < 4; r++) {
            float d = sd[r], a = sa[r];
#pragma unroll
            for (int off = 1; off < 16; off <<= 1) {
                d += __shfl_xor(d, off, 64);
                a += __shfl_xor(a, off, 64);
            }
            if (l15 == 0)
                *(float2*)(ctab + (size_t)(R + g * 4 + r) * 2) = float2{d, a};
        }
    }
}

// ---------------- fused pair + pin readout ----------------
__global__ __launch_bounds__(256) void k_readout(
    const int* __restrict__ pairs,
    const float* __restrict__ pin_feat,
    const int* __restrict__ pin_net, const int* __restrict__ pin_cell,
    const float* __restrict__ ntab, const float* __restrict__ ctab,
    const float* __restrict__ plw, const float* __restrict__ plb,
    const float* __restrict__ pdw, const float* __restrict__ paw,
    const float* __restrict__ nbd, const float* __restrict__ nba,
    const float* __restrict__ pbd, const float* __restrict__ pba,
    float* __restrict__ out) {
    int i = blockIdx.x * blockDim.x + threadIdx.x;
    if (i < NPAIR) {
        int p0 = pairs[2 * i], p1 = pairs[2 * i + 1];
        float2 x0 = *(const float2*)(ntab + (size_t)p0 * 8);
        float2 x1 = *(const float2*)(ntab + (size_t)p1 * 8 + 2);
        out[i] = softplusf(x0.x + x1.x + nbd[0]);
        out[NPAIR + i] = x0.y + x1.y + nba[0];
    } else if (i < NPAIR + NPIN) {
        int p = i - NPAIR;
        int n = pin_net[p], c = pin_cell[p];
        float2 ns = *(const float2*)(ntab + (size_t)n * 8 + 4);
        float2 cs = *(const float2*)(ctab + (size_t)c * 2);
        float pf[8];
        *(float4*)pf = *(const float4*)(pin_feat + (size_t)p * 8);
        *(float4*)(pf + 4) = *(const float4*)(pin_feat + (size_t)p * 8 + 4);
        float sd = ns.x + cs.x + pbd[0];
        float sa = ns.y + cs.y + pba[0];
#pragma unroll
        for (int j = 0; j < 8; j++) {
            float a = plb[j];
#pragma unroll
            for (int k = 0; k < 8; k++) a = fmaf(pf[k], plw[k * 8 + j], a);
            float hp = ftanh(a);
            sd = fmaf(hp, pdw[64 + j], sd);
            sa = fmaf(hp, paw[64 + j], sa);
        }
        out[2 * NPAIR + p] = softplusf(sd);
        out[2 * NPAIR + NPIN + p] = sa;
    }
}

extern "C" void kernel_launch(void* const* d_in, const int* in_sizes, int n_in,
                              void* d_out, int out_size, void* d_ws, size_t ws_size,
                              hipStream_t stream) {
    const float* cell_feat = (const float*)d_in[0];
    const float* net_feat  = (const float*)d_in[1];
    const float* pin_feat  = (const float*)d_in[2];
    const float* cell_lin_w = (const float*)d_in[3];
    const float* cell_lin_b = (const float*)d_in[4];
    const float* net_lin_w  = (const float*)d_in[5];
    const float* net_lin_b  = (const float*)d_in[6];
    const float* pin_lin_w  = (const float*)d_in[7];
    const float* pin_lin_b  = (const float*)d_in[8];
    const float* pins_w   = (const float*)d_in[9];
    const float* pins_b   = (const float*)d_in[10];
    const float* father_w = (const float*)d_in[11];
    const float* father_b = (const float*)d_in[12];
    const float* son_w    = (const float*)d_in[13];
    const float* son_b    = (const float*)d_in[14];
    const float* cf_node_w = (const float*)d_in[15];
    const float* cf_node_b = (const float*)d_in[16];
    const float* cf_e1_w  = (const float*)d_in[17];
    const float* cf_e1_b  = (const float*)d_in[18];
    const float* cf_e2_w  = (const float*)d_in[19];
    const float* cf_e2_b  = (const float*)d_in[20];
    const float* cf_out_w = (const float*)d_in[21];
    const float* cf_out_b = (const float*)d_in[22];
    const float* net_dis_w   = (const float*)d_in[23];
    const float* net_dis_b   = (const float*)d_in[24];
    const float* net_angle_w = (const float*)d_in[25];
    const float* net_angle_b = (const float*)d_in[26];
    const float* pin_dis_w   = (const float*)d_in[27];
    const float* pin_dis_b   = (const float*)d_in[28];
    const float* pin_angle_w = (const float*)d_in[29];
    const float* pin_angle_b = (const float*)d_in[30];
    const int* pin_net = (const int*)d_in[31];
    const int* pin_cell = (const int*)d_in[32];
    const int* nn_src = (const int*)d_in[33];
    const int* nn_dst = (const int*)d_in[34];
    const int* pairs = (const int*)d_in[35];

    u16* ws16 = (u16*)d_ws;
    const size_t SZ = (size_t)NNET * 64;
    u16* h_cell   = ws16;
    u16* acc_cell = ws16;
    u16* h_net    = ws16 + SZ;
    u16* accP     = ws16 + 2 * SZ;
    u16* accF     = ws16 + 3 * SZ;
    u16* accS     = ws16 + 4 * SZ;
    u16* etab     = ws16 + 5 * SZ;
    u16* hv       = ws16 + 10 * SZ;
    u32* tail = (u32*)(ws16 + 11 * SZ);
    u32* cnt    = tail;
    u32* Sarr   = cnt + NSCAN;
    u32* rankNp = Sarr + NSCAN + 2;
    u32* rankC  = rankNp + NPIN;
    u32* rankD  = rankC + NPIN;
    u32* rankS  = rankD + NNN;
    u32* colC   = rankS + NNN;
    u32* colS   = colC + NPIN;
    u32* colD   = colS + NNN;
    u64* colPN  = (u64*)(colD + NNN);
    u32* bsum   = (u32*)(colPN + NPIN);
    float* deg  = (float*)(bsum + 512);
    float* rNp = deg;
    float* rC  = deg + NNET;
    float* rD  = deg + 2 * NNET;
    float* rS  = deg + 3 * NNET;
    float* ntab = deg + NSCAN;
    float* ctab = ntab + (size_t)NNET * 8;

    hipMemsetAsync(cnt, 0, NSCAN * sizeof(u32), stream);

    k_degrees<<<(NPIN + 255) / 256, 256, 0, stream>>>(
        pin_cell, pin_net, nn_src, nn_dst, cnt, rankNp, rankC, rankD, rankS);
    k_lin16_all<<<2048, 256, 0, stream>>>(cell_feat, net_feat,
                                          cell_lin_w, cell_lin_b, net_lin_w, net_lin_b,
                                          h_cell, h_net);

    k_scan1<<<SCAN_BLOCKS, 256, 0, stream>>>(cnt, Sarr, bsum, deg);
    k_scan2<<<1, 512, 0, stream>>>(bsum);
    k_scan3<<<(NSCAN + 255) / 256, 256, 0, stream>>>(Sarr, bsum);
    k_place_part<<<2048, 256, 0, stream>>>(pin_cell, pin_net, nn_src, nn_dst,
                                           Sarr, rankNp, rankC, rankD, rankS,
                                           colC, colPN, colS, colD);

    k_emlp<<<2048, 256, 0, stream>>>(pin_feat, colPN, cf_e1_w, cf_e1_b, cf_e2_w, cf_e2_b, etab);
    k_mm64hv<<<1024, 256, 0, stream>>>(h_net, cf_node_w, cf_node_b, hv, NNET);
    k_gatherP<<<2048, 256, 0, stream>>>(Sarr, colC, h_cell, rC, accP);
    k_gatherFS<<<2048, 256, 0, stream>>>(Sarr, colS, colD, h_net, rD, rS, accF, accS);

    k_combine3<<<512, 256, 0, stream>>>(accP, pins_w, pins_b,
                                        accF, father_w, father_b,
                                        accS, son_w, son_b,
                                        rNp, rD, rS,
                                        net_dis_w, net_angle_w, pin_dis_w, pin_angle_w,
                                        ntab, NNET);

    k_gatherCell<<<2048, 256, 0, stream>>>(Sarr, colPN, etab, hv, acc_cell);

    k_mm64c<<<512, 256, 0, stream>>>(acc_cell, cf_out_w, cf_out_b,
                                     pin_dis_w, pin_angle_w, ctab, NCELL);

    float* out = (float*)d_out;
    k_readout<<<(NPAIR + NPIN + 255) / 256, 256, 0, stream>>>(
        pairs, pin_feat, pin_net, pin_cell, ntab, ctab,
        pin_lin_w, pin_lin_b, pin_dis_w, pin_angle_w,
        net_dis_b, net_angle_b, pin_dis_b, pin_angle_b, out);
}

// Round 19
// 288.497 us; speedup vs baseline: 1.0823x; 1.0691x over previous
//
#include <hip/hip_runtime.h>
#include <math.h>

#define NCELL 100000
#define NNET  100000
#define NPIN  500000
#define NNN   200000
#define NPAIR 500000
#define NSCAN (4 * NNET)
#define SCAN_BLOCKS ((NSCAN + 1023) / 1024)    // 391
#define PART_SZ ((NNET + 7) / 8)               // 12500

typedef __attribute__((ext_vector_type(8))) short short8;
typedef __attribute__((ext_vector_type(4))) float f32x4;
typedef unsigned short u16;
typedef unsigned int u32;
typedef unsigned long long u64;

__device__ __forceinline__ u16 f2bf(float x) {
    union { float f; u32 u; } v; v.f = x;
    u32 r = (v.u + 0x7FFF + ((v.u >> 16) & 1)) >> 16;
    return (u16)r;
}
__device__ __forceinline__ float bf2f(u16 u) {
    union { u32 u; float f; } v; v.u = ((u32)u) << 16; return v.f;
}
__device__ __forceinline__ u32 cvtpk(float lo, float hi) {
    u32 r;
    asm("v_cvt_pk_bf16_f32 %0, %1, %2" : "=v"(r) : "v"(lo), "v"(hi));
    return r;
}
__device__ __forceinline__ u16 f2bf_fast(float v) {
    return (u16)(cvtpk(v, v) & 0xffffu);
}
__device__ __forceinline__ float plo(u32 h) { return bf2f((u16)(h & 0xffff)); }
__device__ __forceinline__ float phi(u32 h) { return bf2f((u16)(h >> 16)); }
// packed bf16x2 atomic add; no "memory" clobber (write-only accumulator)
__device__ __forceinline__ void pk_add(u16* addr, u32 data) {
    asm volatile("global_atomic_pk_add_bf16 %0, %1, off"
                 :: "v"((unsigned long long)(uintptr_t)addr), "v"(data));
}

__device__ __forceinline__ float softplusf(float x) {
    return fmaxf(x, 0.f) + __logf(1.f + __expf(-fabsf(x)));
}
__device__ __forceinline__ float sspf(float x) {
    return softplusf(x) - 0.69314718055994530942f;
}
__device__ __forceinline__ float ftanh(float x) {
    float xc = fminf(fmaxf(x, -9.f), 9.f);
    float e = __expf(2.f * xc);
    return (e - 1.f) * __builtin_amdgcn_rcpf(e + 1.f);
}

__device__ __forceinline__ short8 load_bfrag(const float* __restrict__ W,
                                             int kt, int nt, int lane) {
    int k0 = kt * 32 + ((lane >> 4) & 3) * 8;
    int c = nt * 16 + (lane & 15);
    short8 f;
#pragma unroll
    for (int j = 0; j < 8; j++) f[j] = (short)f2bf(W[(k0 + j) * 64 + c]);
    return f;
}

// ---------------- degrees + rank capture (full grid, 1 edge/thread) ----------------
__global__ void k_degrees(const int* __restrict__ pin_cell, const int* __restrict__ pin_net,
                          const int* __restrict__ nn_src, const int* __restrict__ nn_dst,
                          u32* __restrict__ cnt,
                          u32* __restrict__ rankNp, u32* __restrict__ rankC,
                          u32* __restrict__ rankD, u32* __restrict__ rankS) {
    int i = blockIdx.x * blockDim.x + threadIdx.x;
    if (i < NPIN) {
        rankNp[i] = atomicAdd(&cnt[pin_net[i]], 1u);
        rankC[i]  = atomicAdd(&cnt[NNET + pin_cell[i]], 1u);
    }
    if (i < NNN) {
        rankD[i] = atomicAdd(&cnt[2 * NNET + nn_dst[i]], 1u);
        rankS[i] = atomicAdd(&cnt[3 * NNET + nn_src[i]], 1u);
    }
}

// ---------------- input linears: cells (unscaled) + nets, bf16 out ----------------
__global__ __launch_bounds__(256) void k_lin16_all(
    const float* __restrict__ cf, const float* __restrict__ nf,
    const float* __restrict__ Wc, const float* __restrict__ bc,
    const float* __restrict__ Wn, const float* __restrict__ bn,
    u16* __restrict__ h_cell, u16* __restrict__ h_net) {
    int tid = threadIdx.x, lane = tid & 63, w = tid >> 6;
    float wc[16], wn[16];
#pragma unroll
    for (int k = 0; k < 16; k++) { wc[k] = Wc[k * 64 + lane]; wn[k] = Wn[k * 64 + lane]; }
    float bC = bc[lane], bN = bn[lane];
    int wave = blockIdx.x * 4 + w, nw = gridDim.x * 4;
    for (int r = wave; r < NCELL; r += nw) {
        const float4* ip = (const float4*)(cf + (size_t)r * 16);
        float4 a = ip[0], bv = ip[1], c = ip[2], d = ip[3];
        float acc = bC;
        acc = fmaf(a.x, wc[0], acc);  acc = fmaf(a.y, wc[1], acc);
        acc = fmaf(a.z, wc[2], acc);  acc = fmaf(a.w, wc[3], acc);
        acc = fmaf(bv.x, wc[4], acc); acc = fmaf(bv.y, wc[5], acc);
        acc = fmaf(bv.z, wc[6], acc); acc = fmaf(bv.w, wc[7], acc);
        acc = fmaf(c.x, wc[8], acc);  acc = fmaf(c.y, wc[9], acc);
        acc = fmaf(c.z, wc[10], acc); acc = fmaf(c.w, wc[11], acc);
        acc = fmaf(d.x, wc[12], acc); acc = fmaf(d.y, wc[13], acc);
        acc = fmaf(d.z, wc[14], acc); acc = fmaf(d.w, wc[15], acc);
        float v = ftanh(acc);
        float vp = __shfl_xor(v, 1, 64);
        if (!(lane & 1))
            *(u32*)(h_cell + (size_t)r * 64 + lane) = cvtpk(v, vp);
    }
    for (int r = wave; r < NNET; r += nw) {
        const float4* ip = (const float4*)(nf + (size_t)r * 16);
        float4 a = ip[0], bv = ip[1], c = ip[2], d = ip[3];
        float acc = bN;
        acc = fmaf(a.x, wn[0], acc);  acc = fmaf(a.y, wn[1], acc);
        acc = fmaf(a.z, wn[2], acc);  acc = fmaf(a.w, wn[3], acc);
        acc = fmaf(bv.x, wn[4], acc); acc = fmaf(bv.y, wn[5], acc);
        acc = fmaf(bv.z, wn[6], acc); acc = fmaf(bv.w, wn[7], acc);
        acc = fmaf(c.x, wn[8], acc);  acc = fmaf(c.y, wn[9], acc);
        acc = fmaf(c.z, wn[10], acc); acc = fmaf(c.w, wn[11], acc);
        acc = fmaf(d.x, wn[12], acc); acc = fmaf(d.y, wn[13], acc);
        acc = fmaf(d.z, wn[14], acc); acc = fmaf(d.w, wn[15], acc);
        float v = ftanh(acc);
        float vp = __shfl_xor(v, 1, 64);
        if (!(lane & 1))
            *(u32*)(h_net + (size_t)r * 64 + lane) = cvtpk(v, vp);
    }
}

// ---------------- scan1 + deg_fin fused ----------------
__global__ __launch_bounds__(256) void k_scan1(const u32* __restrict__ in,
                                               u32* __restrict__ out, u32* __restrict__ bsum,
                                               float* __restrict__ deg) {
    __shared__ u32 sc[256];
    int t = threadIdx.x;
    int base = blockIdx.x * 1024 + t * 4;
    u32 v0 = base + 0 < NSCAN ? in[base + 0] : 0;
    u32 v1 = base + 1 < NSCAN ? in[base + 1] : 0;
    u32 v2 = base + 2 < NSCAN ? in[base + 2] : 0;
    u32 v3 = base + 3 < NSCAN ? in[base + 3] : 0;
    if (base + 0 < NSCAN) deg[base + 0] = rsqrtf((float)max(v0, 1u));
    if (base + 1 < NSCAN) deg[base + 1] = rsqrtf((float)max(v1, 1u));
    if (base + 2 < NSCAN) deg[base + 2] = rsqrtf((float)max(v2, 1u));
    if (base + 3 < NSCAN) deg[base + 3] = rsqrtf((float)max(v3, 1u));
    u32 s = v0 + v1 + v2 + v3;
    sc[t] = s; __syncthreads();
    for (int off = 1; off < 256; off <<= 1) {
        u32 x = (t >= off) ? sc[t - off] : 0; __syncthreads();
        sc[t] += x; __syncthreads();
    }
    u32 excl = sc[t] - s;
    if (base + 0 < NSCAN) out[base + 0] = excl;
    if (base + 1 < NSCAN) out[base + 1] = excl + v0;
    if (base + 2 < NSCAN) out[base + 2] = excl + v0 + v1;
    if (base + 3 < NSCAN) out[base + 3] = excl + v0 + v1 + v2;
    if (t == 255) bsum[blockIdx.x] = sc[255];
}

__global__ __launch_bounds__(512) void k_scan2(u32* __restrict__ bsum) {
    __shared__ u32 sc[512];
    int t = threadIdx.x;
    u32 v = (t < SCAN_BLOCKS) ? bsum[t] : 0;
    sc[t] = v; __syncthreads();
    for (int off = 1; off < 512; off <<= 1) {
        u32 x = (t >= off) ? sc[t - off] : 0; __syncthreads();
        sc[t] += x; __syncthreads();
    }
    if (t < SCAN_BLOCKS) bsum[t] = sc[t] - v;
}

__global__ __launch_bounds__(256) void k_scan3(u32* __restrict__ S, const u32* __restrict__ bsum) {
    int i = blockIdx.x * blockDim.x + threadIdx.x;
    if (i < NSCAN) S[i] = S[i] + bsum[i >> 10];
    if (i == 0) S[NSCAN] = 2u * NPIN + 2u * NNN;
}

// ---------------- CSR placement, atomic-free, XCD-partitioned ----------------
// colPNC packs pin | net<<20 | cell<<40
__global__ __launch_bounds__(256) void k_place_part(
    const int* __restrict__ pin_cell, const int* __restrict__ pin_net,
    const int* __restrict__ nn_src, const int* __restrict__ nn_dst,
    const u32* __restrict__ S,
    const u32* __restrict__ rankNp, const u32* __restrict__ rankC,
    const u32* __restrict__ rankD, const u32* __restrict__ rankS,
    u32* __restrict__ colC, u64* __restrict__ colPNC,
    u32* __restrict__ colS, u32* __restrict__ colD) {
    int part = blockIdx.x & 7;
    int grp = blockIdx.x >> 3;
    int ngrp = gridDim.x >> 3;
    int lo = part * PART_SZ, hi = lo + PART_SZ;
    int stride = ngrp * 256;
    for (int e = grp * 256 + threadIdx.x; e < NPIN; e += stride) {
        int n = pin_net[e], c = pin_cell[e];
        if (n >= lo && n < hi)
            colC[S[n] + rankNp[e]] = (u32)c;
        if (c >= lo && c < hi)
            colPNC[S[NNET + c] + rankC[e] - NPIN] =
                (u64)(u32)e | ((u64)(u32)n << 20) | ((u64)(u32)c << 40);
    }
    for (int i = grp * 256 + threadIdx.x; i < NNN; i += stride) {
        int s = nn_src[i], d = nn_dst[i];
        if (d >= lo && d < hi)
            colS[S[2 * NNET + d] + rankD[i] - 2u * NPIN] = (u32)s;
        if (s >= lo && s < hi)
            colD[S[3 * NNET + s] + rankS[i] - (2u * NPIN + NNN)] = (u32)d;
    }
}

// ---------------- e-MLP fused with cell-sum (tile-local segmented reduction) ----------------
__global__ __launch_bounds__(256, 4) void k_emlp_fused(
    const float* __restrict__ pin_feat, const u64* __restrict__ colPNC,
    const float* __restrict__ E1, const float* __restrict__ b1,
    const float* __restrict__ E2, const float* __restrict__ b2,
    const u16* __restrict__ hv, u16* __restrict__ acc) {
    __shared__ __align__(16) u16 sm[4][1024];       // bf16 t1 transpose buffer
    __shared__ float smf[4][16][64];                // f32 e*hv products
    __shared__ u64 smc[4][16];                      // tile descriptors
    int tid = threadIdx.x, lane = tid & 63, w = tid >> 6;
    int l15 = lane & 15, g = (lane >> 4) & 3;
    short8 B1[4];
#pragma unroll
    for (int nt = 0; nt < 4; nt++) {
        short8 f = {0, 0, 0, 0, 0, 0, 0, 0};
        if (lane < 16) {
            int c = nt * 16 + l15;
#pragma unroll
            for (int j = 0; j < 8; j++) f[j] = (short)f2bf(E1[j * 64 + c]);
        }
        B1[nt] = f;
    }
    short8 B2[2][4];
#pragma unroll
    for (int kt = 0; kt < 2; kt++)
#pragma unroll
        for (int nt = 0; nt < 4; nt++) B2[kt][nt] = load_bfrag(E2, kt, nt, lane);
    float bb1[4], bb2[4];
#pragma unroll
    for (int nt = 0; nt < 4; nt++) {
        bb1[nt] = b1[nt * 16 + l15];
        bb2[nt] = b2[nt * 16 + l15];
    }
    int wave = blockIdx.x * 4 + w, nwave = gridDim.x * 4;
    const int ntile = NPIN >> 4;    // 31250 exact
    f32x4 z = {0.f, 0.f, 0.f, 0.f};
    for (int t = wave; t < ntile; t += nwave) {
        int P = t << 4;
        short8 a1 = {0, 0, 0, 0, 0, 0, 0, 0};
        if (lane < 16) {
            u64 v = colPNC[P + lane];
            smc[w][lane] = v;
            u32 p = (u32)(v & 0xFFFFFu);
            const float4* q = (const float4*)(pin_feat + (size_t)p * 8);
            float4 u0 = q[0], u1 = q[1];
            u32 w01 = cvtpk(u0.x, u0.y), w23 = cvtpk(u0.z, u0.w);
            u32 w45 = cvtpk(u1.x, u1.y), w67 = cvtpk(u1.z, u1.w);
            a1[0] = (short)(w01 & 0xffff); a1[1] = (short)(w01 >> 16);
            a1[2] = (short)(w23 & 0xffff); a1[3] = (short)(w23 >> 16);
            a1[4] = (short)(w45 & 0xffff); a1[5] = (short)(w45 >> 16);
            a1[6] = (short)(w67 & 0xffff); a1[7] = (short)(w67 >> 16);
        }
#pragma unroll
        for (int nt = 0; nt < 4; nt++) {
            f32x4 c1 = __builtin_amdgcn_mfma_f32_16x16x32_bf16(a1, B1[nt], z, 0, 0, 0);
#pragma unroll
            for (int r = 0; r < 4; r++) {
                int row = g * 4 + r;
                int col = nt * 16 + l15;
                sm[w][row * 64 + (col ^ ((row & 7) << 3))] = f2bf_fast(sspf(c1[r] + bb1[nt]));
            }
        }
        short8 a2[2];
#pragma unroll
        for (int kt = 0; kt < 2; kt++) {
            int idx = l15 * 64 + ((kt * 32 + g * 8) ^ ((l15 & 7) << 3));
            a2[kt] = *(const short8*)&sm[w][idx];
        }
        f32x4 ef[4];
#pragma unroll
        for (int nt = 0; nt < 4; nt++) {
            f32x4 e = __builtin_amdgcn_mfma_f32_16x16x32_bf16(a2[0], B2[0][nt], z, 0, 0, 0);
            e = __builtin_amdgcn_mfma_f32_16x16x32_bf16(a2[1], B2[1][nt], e, 0, 0, 0);
#pragma unroll
            for (int r = 0; r < 4; r++) ef[nt][r] = sspf(e[r] + bb2[nt]);
        }
        // products: smf[row][col] = e * hv[net(row)][col]
#pragma unroll
        for (int r = 0; r < 4; r++) {
            u64 v = smc[w][g * 4 + r];
            u32 net = (u32)((v >> 20) & 0xFFFFFu);
#pragma unroll
            for (int nt = 0; nt < 4; nt++) {
                float h = bf2f(hv[(size_t)net * 64 + nt * 16 + l15]);
                smf[w][g * 4 + r][nt * 16 + l15] = ef[nt][r] * h;
            }
        }
        // wave-uniform segmented reduction over the 16 rows; lane = col
        float a = smf[w][0][lane];
        u32 prev = (u32)(smc[w][0] >> 40);
        int r0 = 0;
#pragma unroll
        for (int r = 1; r < 16; r++) {
            u32 cr = (u32)(smc[w][r] >> 40);
            if (cr != prev) {
                if (r0 > 0) {   // interior segment: exclusive to this tile
                    acc[(size_t)prev * 64 + lane] = f2bf_fast(a);
                } else {        // may extend into previous tile
                    float ap = __shfl_xor(a, 1, 64);
                    if (!(lane & 1)) pk_add(acc + (size_t)prev * 64 + lane, cvtpk(a, ap));
                }
                a = smf[w][r][lane];
                prev = cr;
                r0 = r;
            } else {
                a += smf[w][r][lane];
            }
        }
        {   // final segment: may extend into next tile
            float ap = __shfl_xor(a, 1, 64);
            if (!(lane & 1)) pk_add(acc + (size_t)prev * 64 + lane, cvtpk(a, ap));
        }
    }
}

// ---------------- hv = h_net @ cf_node_w + b ----------------
__global__ __launch_bounds__(256, 4) void k_mm64hv(
    const u16* __restrict__ in, const float* __restrict__ W,
    const float* __restrict__ b, u16* __restrict__ out, int n) {
    int tid = threadIdx.x, lane = tid & 63, w = tid >> 6;
    int l15 = lane & 15, g = (lane >> 4) & 3;
    short8 Bf[2][4];
    float bias[4];
#pragma unroll
    for (int kt = 0; kt < 2; kt++)
#pragma unroll
        for (int nt = 0; nt < 4; nt++) Bf[kt][nt] = load_bfrag(W, kt, nt, lane);
#pragma unroll
    for (int nt = 0; nt < 4; nt++) bias[nt] = b[nt * 16 + l15];
    int wave = blockIdx.x * 4 + w, nwave = gridDim.x * 4;
    int ntile = n >> 4;
    f32x4 z = {0.f, 0.f, 0.f, 0.f};
    for (int t = wave; t < ntile; t += nwave) {
        int R = t << 4;
        const u16* rb = in + (size_t)(R + l15) * 64;
        short8 a0 = *(const short8*)(rb + g * 8);
        short8 a1 = *(const short8*)(rb + 32 + g * 8);
#pragma unroll
        for (int nt = 0; nt < 4; nt++) {
            f32x4 acc = __builtin_amdgcn_mfma_f32_16x16x32_bf16(a0, Bf[0][nt], z, 0, 0, 0);
            acc = __builtin_amdgcn_mfma_f32_16x16x32_bf16(a1, Bf[1][nt], acc, 0, 0, 0);
#pragma unroll
            for (int r = 0; r < 4; r++) {
                float v = acc[r] + bias[nt];
                float vp = __shfl_xor(v, 1, 64);
                if (!(lane & 1))
                    *(u32*)(out + (size_t)(R + g * 4 + r) * 64 + nt * 16 + l15) = cvtpk(v, vp);
            }
        }
    }
}

// ---------------- gather-sum: accP[n] = sum rC[c]*h_cell[c] ----------------
__global__ __launch_bounds__(256) void k_gatherP(
    const u32* __restrict__ S, const u32* __restrict__ colC,
    const u16* __restrict__ h_cell, const float* __restrict__ rCv,
    u16* __restrict__ accP) {
    int l32 = threadIdx.x & 31, off2 = l32 * 2;
    int slot = blockIdx.x * 8 + (threadIdx.x >> 5), ns = gridDim.x * 8;
    for (int n = slot; n < NNET; n += ns) {
        u32 b0 = S[n], b1 = S[n + 1];
        float fa = 0.f, fb = 0.f, ga = 0.f, gb = 0.f;
        u32 k = b0;
        for (; k + 1 < b1; k += 2) {
            u32 c0 = colC[k], c1 = colC[k + 1];
            float r0 = rCv[c0], r1 = rCv[c1];
            u32 h0 = *(const u32*)(h_cell + (size_t)c0 * 64 + off2);
            u32 h1 = *(const u32*)(h_cell + (size_t)c1 * 64 + off2);
            fa = fmaf(plo(h0), r0, fa); fb = fmaf(phi(h0), r0, fb);
            ga = fmaf(plo(h1), r1, ga); gb = fmaf(phi(h1), r1, gb);
        }
        if (k < b1) {
            u32 c0 = colC[k];
            float r0 = rCv[c0];
            u32 h0 = *(const u32*)(h_cell + (size_t)c0 * 64 + off2);
            fa = fmaf(plo(h0), r0, fa); fb = fmaf(phi(h0), r0, fb);
        }
        *(u32*)(accP + (size_t)n * 64 + off2) = cvtpk(fa + ga, fb + gb);
    }
}

// ---------------- gather-sum for both nn relations ----------------
__global__ __launch_bounds__(256) void k_gatherFS(
    const u32* __restrict__ S, const u32* __restrict__ colS, const u32* __restrict__ colD,
    const u16* __restrict__ h_net, const float* __restrict__ rDv, const float* __restrict__ rSv,
    u16* __restrict__ accF, u16* __restrict__ accS) {
    int l32 = threadIdx.x & 31, off2 = l32 * 2;
    int slot = blockIdx.x * 8 + (threadIdx.x >> 5), ns = gridDim.x * 8;
    for (int r = slot; r < 2 * NNET; r += ns) {
        if (r < NNET) {
            int d = r;
            u32 b0 = S[2 * NNET + d] - 2u * NPIN, b1 = S[2 * NNET + d + 1] - 2u * NPIN;
            float fa = 0.f, fb = 0.f, ga = 0.f, gb = 0.f;
            u32 k = b0;
            for (; k + 1 < b1; k += 2) {
                u32 s0 = colS[k], s1 = colS[k + 1];
                float c0 = rSv[s0], c1 = rSv[s1];
                u32 h0 = *(const u32*)(h_net + (size_t)s0 * 64 + off2);
                u32 h1 = *(const u32*)(h_net + (size_t)s1 * 64 + off2);
                fa = fmaf(plo(h0), c0, fa); fb = fmaf(phi(h0), c0, fb);
                ga = fmaf(plo(h1), c1, ga); gb = fmaf(phi(h1), c1, gb);
            }
            if (k < b1) {
                u32 s0 = colS[k];
                float c0 = rSv[s0];
                u32 h0 = *(const u32*)(h_net + (size_t)s0 * 64 + off2);
                fa = fmaf(plo(h0), c0, fa); fb = fmaf(phi(h0), c0, fb);
            }
            *(u32*)(accF + (size_t)d * 64 + off2) = cvtpk(fa + ga, fb + gb);
        } else {
            int s = r - NNET;
            u32 b0 = S[3 * NNET + s] - (2u * NPIN + NNN), b1 = S[3 * NNET + s + 1] - (2u * NPIN + NNN);
            float fa = 0.f, fb = 0.f, ga = 0.f, gb = 0.f;
            u32 k = b0;
            for (; k + 1 < b1; k += 2) {
                u32 d0 = colD[k], d1 = colD[k + 1];
                float c0 = rDv[d0], c1 = rDv[d1];
                u32 h0 = *(const u32*)(h_net + (size_t)d0 * 64 + off2);
                u32 h1 = *(const u32*)(h_net + (size_t)d1 * 64 + off2);
                fa = fmaf(plo(h0), c0, fa); fb = fmaf(phi(h0), c0, fb);
                ga = fmaf(plo(h1), c1, ga); gb = fmaf(phi(h1), c1, gb);
            }
            if (k < b1) {
                u32 d0 = colD[k];
                float c0 = rDv[d0];
                u32 h0 = *(const u32*)(h_net + (size_t)d0 * 64 + off2);
                fa = fmaf(plo(h0), c0, fa); fb = fmaf(phi(h0), c0, fb);
            }
            *(u32*)(accS + (size_t)s * 64 + off2) = cvtpk(fa + ga, fb + gb);
        }
    }
}

// ---------------- 3-relation combine + row scales + fused ntab dots ----------------
__global__ __launch_bounds__(256, 2) void k_combine3(
    const u16* __restrict__ A0, const float* __restrict__ W0, const float* __restrict__ b0,
    const u16* __restrict__ A1, const float* __restrict__ W1, const float* __restrict__ b1,
    const u16* __restrict__ A2, const float* __restrict__ W2, const float* __restrict__ b2,
    const float* __restrict__ sc0, const float* __restrict__ sc1, const float* __restrict__ sc2,
    const float* __restrict__ ndw, const float* __restrict__ naw,
    const float* __restrict__ pdw, const float* __restrict__ paw,
    float* __restrict__ ntab, int n) {
    int tid = threadIdx.x, lane = tid & 63, w = tid >> 6;
    int l15 = lane & 15, g = (lane >> 4) & 3;
    const float* Ws[3] = {W0, W1, W2};
    const float* bs[3] = {b0, b1, b2};
    const u16* As[3] = {A0, A1, A2};
    short8 Bf[3][2][4];
    float bias[3][4];
#pragma unroll
    for (int rel = 0; rel < 3; rel++) {
#pragma unroll
        for (int kt = 0; kt < 2; kt++)
#pragma unroll
            for (int nt = 0; nt < 4; nt++) Bf[rel][kt][nt] = load_bfrag(Ws[rel], kt, nt, lane);
#pragma unroll
        for (int nt = 0; nt < 4; nt++) bias[rel][nt] = bs[rel][nt * 16 + l15];
    }
    float wt[6][4];
#pragma unroll
    for (int nt = 0; nt < 4; nt++) {
        int c = nt * 16 + l15;
        wt[0][nt] = ndw[c];      wt[1][nt] = naw[c];
        wt[2][nt] = ndw[64 + c]; wt[3][nt] = naw[64 + c];
        wt[4][nt] = pdw[c];      wt[5][nt] = paw[c];
    }
    int wave = blockIdx.x * 4 + w, nwave = gridDim.x * 4;
    int ntile = n >> 4;
    f32x4 z = {0.f, 0.f, 0.f, 0.f};
    for (int t = wave; t < ntile; t += nwave) {
        int R = t << 4;
        int rowA = R + l15;
        float s0a[4], s1a[4], s2a[4];
        *(float4*)s0a = *(const float4*)(sc0 + R + g * 4);
        *(float4*)s1a = *(const float4*)(sc1 + R + g * 4);
        *(float4*)s2a = *(const float4*)(sc2 + R + g * 4);
        f32x4 res[4];
#pragma unroll
        for (int rel = 0; rel < 3; rel++) {
            const u16* rb = As[rel] + (size_t)rowA * 64;
            short8 a0 = *(const short8*)(rb + g * 8);
            short8 a1 = *(const short8*)(rb + 32 + g * 8);
            const float* sa = (rel == 0) ? s0a : (rel == 1) ? s1a : s2a;
#pragma unroll
            for (int nt = 0; nt < 4; nt++) {
                f32x4 acc = __builtin_amdgcn_mfma_f32_16x16x32_bf16(a0, Bf[rel][0][nt], z, 0, 0, 0);
                acc = __builtin_amdgcn_mfma_f32_16x16x32_bf16(a1, Bf[rel][1][nt], acc, 0, 0, 0);
                if (rel == 0) {
#pragma unroll
                    for (int r = 0; r < 4; r++) res[nt][r] = sa[r] * acc[r] + bias[0][nt];
                } else {
#pragma unroll
                    for (int r = 0; r < 4; r++)
                        res[nt][r] = fmaxf(res[nt][r], sa[r] * acc[r] + bias[rel][nt]);
                }
            }
        }
#pragma unroll
        for (int r = 0; r < 4; r++) {
            float a0 = 0.f, a1 = 0.f, a2 = 0.f, a3 = 0.f, a4 = 0.f, a5 = 0.f;
#pragma unroll
            for (int nt = 0; nt < 4; nt++) {
                float v = res[nt][r];
                a0 = fmaf(v, wt[0][nt], a0);
                a1 = fmaf(v, wt[1][nt], a1);
                a2 = fmaf(v, wt[2][nt], a2);
                a3 = fmaf(v, wt[3][nt], a3);
                a4 = fmaf(v, wt[4][nt], a4);
                a5 = fmaf(v, wt[5][nt], a5);
            }
#pragma unroll
            for (int off = 1; off < 16; off <<= 1) {
                a0 += __shfl_xor(a0, off, 64);
                a1 += __shfl_xor(a1, off, 64);
                a2 += __shfl_xor(a2, off, 64);
                a3 += __shfl_xor(a3, off, 64);
                a4 += __shfl_xor(a4, off, 64);
                a5 += __shfl_xor(a5, off, 64);
            }
            if (l15 == 0) {
                float* tp = ntab + (size_t)(R + g * 4 + r) * 8;
                *(float2*)tp = float2{a0, a1};
                *(float2*)(tp + 2) = float2{a2, a3};
                *(float2*)(tp + 4) = float2{a4, a5};
            }
        }
    }
}

// ---------------- cell out-layer: ssp(acc @ W + b) fused with ctab dots ----------------
__global__ __launch_bounds__(256, 3) void k_mm64c(
    const u16* __restrict__ in, const float* __restrict__ W, const float* __restrict__ b,
    const float* __restrict__ pdw, const float* __restrict__ paw,
    float* __restrict__ ctab, int n) {
    int tid = threadIdx.x, lane = tid & 63, w = tid >> 6;
    int l15 = lane & 15, g = (lane >> 4) & 3;
    short8 Bf[2][4];
    float bias[4], wdv[4], wav[4];
#pragma unroll
    for (int kt = 0; kt < 2; kt++)
#pragma unroll
        for (int nt = 0; nt < 4; nt++) Bf[kt][nt] = load_bfrag(W, kt, nt, lane);
#pragma unroll
    for (int nt = 0; nt < 4; nt++) {
        int c = nt * 16 + l15;
        bias[nt] = b[c];
        wdv[nt] = pdw[72 + c];
        wav[nt] = paw[72 + c];
    }
    int wave = blockIdx.x * 4 + w, nwave = gridDim.x * 4;
    int ntile = n >> 4;
    f32x4 z = {0.f, 0.f, 0.f, 0.f};
    for (int t = wave; t < ntile; t += nwave) {
        int R = t << 4;
        const u16* rb = in + (size_t)(R + l15) * 64;
        short8 a0 = *(const short8*)(rb + g * 8);
        short8 a1 = *(const short8*)(rb + 32 + g * 8);
        float sd[4] = {0.f, 0.f, 0.f, 0.f}, sa[4] = {0.f, 0.f, 0.f, 0.f};
#pragma unroll
        for (int nt = 0; nt < 4; nt++) {
            f32x4 acc = __builtin_amdgcn_mfma_f32_16x16x32_bf16(a0, Bf[0][nt], z, 0, 0, 0);
            acc = __builtin_amdgcn_mfma_f32_16x16x32_bf16(a1, Bf[1][nt], acc, 0, 0, 0);
#pragma unroll
            for (int r = 0; r < 4; r++) {
                float v = sspf(acc[r] + bias[nt]);
                sd[r] = fmaf(v, wdv[nt], sd[r]);
                sa[r] = fmaf(v, wav[nt], sa[r]);
            }
        }
#pragma unroll
        for (int r = 0; r < 4; r++) {
            float d = sd[r], a = sa[r];
#pragma unroll
            for (int off = 1; off < 16; off <<= 1) {
                d += __shfl_xor(d, off, 64);
                a += __shfl_xor(a, off, 64);
            }
            if (l15 == 0)
                *(float2*)(ctab + (size_t)(R + g * 4 + r) * 2) = float2{d, a};
        }
    }
}

// ---------------- fused pair + pin readout ----------------
__global__ __launch_bounds__(256) void k_readout(
    const int* __restrict__ pairs,
    const float* __restrict__ pin_feat,
    const int* __restrict__ pin_net, const int* __restrict__ pin_cell,
    const float* __restrict__ ntab, const float* __restrict__ ctab,
    const float* __restrict__ plw, const float* __restrict__ plb,
    const float* __restrict__ pdw, const float* __restrict__ paw,
    const float* __restrict__ nbd, const float* __restrict__ nba,
    const float* __restrict__ pbd, const float* __restrict__ pba,
    float* __restrict__ out) {
    int i = blockIdx.x * blockDim.x + threadIdx.x;
    if (i < NPAIR) {
        int p0 = pairs[2 * i], p1 = pairs[2 * i + 1];
        float2 x0 = *(const float2*)(ntab + (size_t)p0 * 8);
        float2 x1 = *(const float2*)(ntab + (size_t)p1 * 8 + 2);
        out[i] = softplusf(x0.x + x1.x + nbd[0]);
        out[NPAIR + i] = x0.y + x1.y + nba[0];
    } else if (i < NPAIR + NPIN) {
        int p = i - NPAIR;
        int n = pin_net[p], c = pin_cell[p];
        float2 ns = *(const float2*)(ntab + (size_t)n * 8 + 4);
        float2 cs = *(const float2*)(ctab + (size_t)c * 2);
        float pf[8];
        *(float4*)pf = *(const float4*)(pin_feat + (size_t)p * 8);
        *(float4*)(pf + 4) = *(const float4*)(pin_feat + (size_t)p * 8 + 4);
        float sd = ns.x + cs.x + pbd[0];
        float sa = ns.y + cs.y + pba[0];
#pragma unroll
        for (int j = 0; j < 8; j++) {
            float a = plb[j];
#pragma unroll
            for (int k = 0; k < 8; k++) a = fmaf(pf[k], plw[k * 8 + j], a);
            float hp = ftanh(a);
            sd = fmaf(hp, pdw[64 + j], sd);
            sa = fmaf(hp, paw[64 + j], sa);
        }
        out[2 * NPAIR + p] = softplusf(sd);
        out[2 * NPAIR + NPIN + p] = sa;
    }
}

extern "C" void kernel_launch(void* const* d_in, const int* in_sizes, int n_in,
                              void* d_out, int out_size, void* d_ws, size_t ws_size,
                              hipStream_t stream) {
    const float* cell_feat = (const float*)d_in[0];
    const float* net_feat  = (const float*)d_in[1];
    const float* pin_feat  = (const float*)d_in[2];
    const float* cell_lin_w = (const float*)d_in[3];
    const float* cell_lin_b = (const float*)d_in[4];
    const float* net_lin_w  = (const float*)d_in[5];
    const float* net_lin_b  = (const float*)d_in[6];
    const float* pin_lin_w  = (const float*)d_in[7];
    const float* pin_lin_b  = (const float*)d_in[8];
    const float* pins_w   = (const float*)d_in[9];
    const float* pins_b   = (const float*)d_in[10];
    const float* father_w = (const float*)d_in[11];
    const float* father_b = (const float*)d_in[12];
    const float* son_w    = (const float*)d_in[13];
    const float* son_b    = (const float*)d_in[14];
    const float* cf_node_w = (const float*)d_in[15];
    const float* cf_node_b = (const float*)d_in[16];
    const float* cf_e1_w  = (const float*)d_in[17];
    const float* cf_e1_b  = (const float*)d_in[18];
    const float* cf_e2_w  = (const float*)d_in[19];
    const float* cf_e2_b  = (const float*)d_in[20];
    const float* cf_out_w = (const float*)d_in[21];
    const float* cf_out_b = (const float*)d_in[22];
    const float* net_dis_w   = (const float*)d_in[23];
    const float* net_dis_b   = (const float*)d_in[24];
    const float* net_angle_w = (const float*)d_in[25];
    const float* net_angle_b = (const float*)d_in[26];
    const float* pin_dis_w   = (const float*)d_in[27];
    const float* pin_dis_b   = (const float*)d_in[28];
    const float* pin_angle_w = (const float*)d_in[29];
    const float* pin_angle_b = (const float*)d_in[30];
    const int* pin_net = (const int*)d_in[31];
    const int* pin_cell = (const int*)d_in[32];
    const int* nn_src = (const int*)d_in[33];
    const int* nn_dst = (const int*)d_in[34];
    const int* pairs = (const int*)d_in[35];

    u16* ws16 = (u16*)d_ws;
    const size_t SZ = (size_t)NNET * 64;
    // u16 slots: 0 h_cell | 1 h_net | 2 accP | 3 accF | 4 accS | 5 acc_cell | 6 hv
    u16* h_cell   = ws16;
    u16* h_net    = ws16 + SZ;
    u16* accP     = ws16 + 2 * SZ;
    u16* accF     = ws16 + 3 * SZ;
    u16* accS     = ws16 + 4 * SZ;
    u16* acc_cell = ws16 + 5 * SZ;
    u16* hv       = ws16 + 6 * SZ;
    u32* tail = (u32*)(ws16 + 7 * SZ);
    u32* cnt    = tail;                        // 400000
    u32* Sarr   = cnt + NSCAN;                 // 400002
    u32* rankNp = Sarr + NSCAN + 2;            // 500000
    u32* rankC  = rankNp + NPIN;               // 500000
    u32* rankD  = rankC + NPIN;                // 200000
    u32* rankS  = rankD + NNN;                 // 200000
    u32* colC   = rankS + NNN;                 // 500000
    u32* colS   = colC + NPIN;                 // 200000
    u32* colD   = colS + NNN;                  // 200000
    u64* colPNC = (u64*)(colD + NNN);          // 500000 u64
    u32* bsum   = (u32*)(colPNC + NPIN);       // 512
    float* deg  = (float*)(bsum + 512);        // NSCAN: [rNp|rC|rD|rS]
    float* rNp = deg;
    float* rC  = deg + NNET;
    float* rD  = deg + 2 * NNET;
    float* rS  = deg + 3 * NNET;
    float* ntab = deg + NSCAN;                 // NNET*8
    float* ctab = ntab + (size_t)NNET * 8;     // NCELL*2

    hipMemsetAsync(cnt, 0, NSCAN * sizeof(u32), stream);
    hipMemsetAsync(acc_cell, 0, SZ * sizeof(u16), stream);   // boundary-atomic accumulator

    k_degrees<<<(NPIN + 255) / 256, 256, 0, stream>>>(
        pin_cell, pin_net, nn_src, nn_dst, cnt, rankNp, rankC, rankD, rankS);
    k_lin16_all<<<2048, 256, 0, stream>>>(cell_feat, net_feat,
                                          cell_lin_w, cell_lin_b, net_lin_w, net_lin_b,
                                          h_cell, h_net);

    k_scan1<<<SCAN_BLOCKS, 256, 0, stream>>>(cnt, Sarr, bsum, deg);
    k_scan2<<<1, 512, 0, stream>>>(bsum);
    k_scan3<<<(NSCAN + 255) / 256, 256, 0, stream>>>(Sarr, bsum);
    k_place_part<<<2048, 256, 0, stream>>>(pin_cell, pin_net, nn_src, nn_dst,
                                           Sarr, rankNp, rankC, rankD, rankS,
                                           colC, colPNC, colS, colD);

    k_mm64hv<<<1024, 256, 0, stream>>>(h_net, cf_node_w, cf_node_b, hv, NNET);
    k_gatherP<<<2048, 256, 0, stream>>>(Sarr, colC, h_cell, rC, accP);
    k_gatherFS<<<2048, 256, 0, stream>>>(Sarr, colS, colD, h_net, rD, rS, accF, accS);

    // e-MLP + cell-sum fused (no etab round-trip)
    k_emlp_fused<<<2048, 256, 0, stream>>>(pin_feat, colPNC,
                                           cf_e1_w, cf_e1_b, cf_e2_w, cf_e2_b,
                                           hv, acc_cell);

    k_combine3<<<512, 256, 0, stream>>>(accP, pins_w, pins_b,
                                        accF, father_w, father_b,
                                        accS, son_w, son_b,
                                        rNp, rD, rS,
                                        net_dis_w, net_angle_w, pin_dis_w, pin_angle_w,
                                        ntab, NNET);

    k_mm64c<<<512, 256, 0, stream>>>(acc_cell, cf_out_w, cf_out_b,
                                     pin_dis_w, pin_angle_w, ctab, NCELL);

    float* out = (float*)d_out;
    k_readout<<<(NPAIR + NPIN + 255) / 256, 256, 0, stream>>>(
        pairs, pin_feat, pin_net, pin_cell, ntab, ctab,
        pin_lin_w, pin_lin_b, pin_dis_w, pin_angle_w,
        net_dis_b, net_angle_b, pin_dis_b, pin_angle_b, out);
}

// Round 20
// 288.261 us; speedup vs baseline: 1.0832x; 1.0008x over previous
//
#include <hip/hip_runtime.h>
#include <math.h>

#define NCELL 100000
#define NNET  100000
#define NPIN  500000
#define NNN   200000
#define NPAIR 500000
#define NSCAN (4 * NNET)
#define SCAN_BLOCKS ((NSCAN + 1023) / 1024)    // 391
#define PART_SZ ((NNET + 7) / 8)               // 12500
#define SMW 65                                  // padded f32 row stride (conflict-free)

typedef __attribute__((ext_vector_type(8))) short short8;
typedef __attribute__((ext_vector_type(4))) float f32x4;
typedef unsigned short u16;
typedef unsigned int u32;
typedef unsigned long long u64;

__device__ __forceinline__ u16 f2bf(float x) {
    union { float f; u32 u; } v; v.f = x;
    u32 r = (v.u + 0x7FFF + ((v.u >> 16) & 1)) >> 16;
    return (u16)r;
}
__device__ __forceinline__ float bf2f(u16 u) {
    union { u32 u; float f; } v; v.u = ((u32)u) << 16; return v.f;
}
__device__ __forceinline__ u32 cvtpk(float lo, float hi) {
    u32 r;
    asm("v_cvt_pk_bf16_f32 %0, %1, %2" : "=v"(r) : "v"(lo), "v"(hi));
    return r;
}
__device__ __forceinline__ u16 f2bf_fast(float v) {
    return (u16)(cvtpk(v, v) & 0xffffu);
}
__device__ __forceinline__ float plo(u32 h) { return bf2f((u16)(h & 0xffff)); }
__device__ __forceinline__ float phi(u32 h) { return bf2f((u16)(h >> 16)); }
// packed bf16x2 atomic add; no "memory" clobber (write-only accumulator)
__device__ __forceinline__ void pk_add(u16* addr, u32 data) {
    asm volatile("global_atomic_pk_add_bf16 %0, %1, off"
                 :: "v"((unsigned long long)(uintptr_t)addr), "v"(data));
}

__device__ __forceinline__ float softplusf(float x) {
    return fmaxf(x, 0.f) + __logf(1.f + __expf(-fabsf(x)));
}
__device__ __forceinline__ float sspf(float x) {
    return softplusf(x) - 0.69314718055994530942f;
}
__device__ __forceinline__ float ftanh(float x) {
    float xc = fminf(fmaxf(x, -9.f), 9.f);
    float e = __expf(2.f * xc);
    return (e - 1.f) * __builtin_amdgcn_rcpf(e + 1.f);
}

__device__ __forceinline__ short8 load_bfrag(const float* __restrict__ W,
                                             int kt, int nt, int lane) {
    int k0 = kt * 32 + ((lane >> 4) & 3) * 8;
    int c = nt * 16 + (lane & 15);
    short8 f;
#pragma unroll
    for (int j = 0; j < 8; j++) f[j] = (short)f2bf(W[(k0 + j) * 64 + c]);
    return f;
}

// ---------------- degrees + rank capture (full grid, 1 edge/thread) ----------------
__global__ void k_degrees(const int* __restrict__ pin_cell, const int* __restrict__ pin_net,
                          const int* __restrict__ nn_src, const int* __restrict__ nn_dst,
                          u32* __restrict__ cnt,
                          u32* __restrict__ rankNp, u32* __restrict__ rankC,
                          u32* __restrict__ rankD, u32* __restrict__ rankS) {
    int i = blockIdx.x * blockDim.x + threadIdx.x;
    if (i < NPIN) {
        rankNp[i] = atomicAdd(&cnt[pin_net[i]], 1u);
        rankC[i]  = atomicAdd(&cnt[NNET + pin_cell[i]], 1u);
    }
    if (i < NNN) {
        rankD[i] = atomicAdd(&cnt[2 * NNET + nn_dst[i]], 1u);
        rankS[i] = atomicAdd(&cnt[3 * NNET + nn_src[i]], 1u);
    }
}

// ---------------- input linears: cells (unscaled) + nets, bf16 out ----------------
__global__ __launch_bounds__(256) void k_lin16_all(
    const float* __restrict__ cf, const float* __restrict__ nf,
    const float* __restrict__ Wc, const float* __restrict__ bc,
    const float* __restrict__ Wn, const float* __restrict__ bn,
    u16* __restrict__ h_cell, u16* __restrict__ h_net) {
    int tid = threadIdx.x, lane = tid & 63, w = tid >> 6;
    float wc[16], wn[16];
#pragma unroll
    for (int k = 0; k < 16; k++) { wc[k] = Wc[k * 64 + lane]; wn[k] = Wn[k * 64 + lane]; }
    float bC = bc[lane], bN = bn[lane];
    int wave = blockIdx.x * 4 + w, nw = gridDim.x * 4;
    for (int r = wave; r < NCELL; r += nw) {
        const float4* ip = (const float4*)(cf + (size_t)r * 16);
        float4 a = ip[0], bv = ip[1], c = ip[2], d = ip[3];
        float acc = bC;
        acc = fmaf(a.x, wc[0], acc);  acc = fmaf(a.y, wc[1], acc);
        acc = fmaf(a.z, wc[2], acc);  acc = fmaf(a.w, wc[3], acc);
        acc = fmaf(bv.x, wc[4], acc); acc = fmaf(bv.y, wc[5], acc);
        acc = fmaf(bv.z, wc[6], acc); acc = fmaf(bv.w, wc[7], acc);
        acc = fmaf(c.x, wc[8], acc);  acc = fmaf(c.y, wc[9], acc);
        acc = fmaf(c.z, wc[10], acc); acc = fmaf(c.w, wc[11], acc);
        acc = fmaf(d.x, wc[12], acc); acc = fmaf(d.y, wc[13], acc);
        acc = fmaf(d.z, wc[14], acc); acc = fmaf(d.w, wc[15], acc);
        float v = ftanh(acc);
        float vp = __shfl_xor(v, 1, 64);
        if (!(lane & 1))
            *(u32*)(h_cell + (size_t)r * 64 + lane) = cvtpk(v, vp);
    }
    for (int r = wave; r < NNET; r += nw) {
        const float4* ip = (const float4*)(nf + (size_t)r * 16);
        float4 a = ip[0], bv = ip[1], c = ip[2], d = ip[3];
        float acc = bN;
        acc = fmaf(a.x, wn[0], acc);  acc = fmaf(a.y, wn[1], acc);
        acc = fmaf(a.z, wn[2], acc);  acc = fmaf(a.w, wn[3], acc);
        acc = fmaf(bv.x, wn[4], acc); acc = fmaf(bv.y, wn[5], acc);
        acc = fmaf(bv.z, wn[6], acc); acc = fmaf(bv.w, wn[7], acc);
        acc = fmaf(c.x, wn[8], acc);  acc = fmaf(c.y, wn[9], acc);
        acc = fmaf(c.z, wn[10], acc); acc = fmaf(c.w, wn[11], acc);
        acc = fmaf(d.x, wn[12], acc); acc = fmaf(d.y, wn[13], acc);
        acc = fmaf(d.z, wn[14], acc); acc = fmaf(d.w, wn[15], acc);
        float v = ftanh(acc);
        float vp = __shfl_xor(v, 1, 64);
        if (!(lane & 1))
            *(u32*)(h_net + (size_t)r * 64 + lane) = cvtpk(v, vp);
    }
}

// ---------------- scan1 + deg_fin fused ----------------
__global__ __launch_bounds__(256) void k_scan1(const u32* __restrict__ in,
                                               u32* __restrict__ out, u32* __restrict__ bsum,
                                               float* __restrict__ deg) {
    __shared__ u32 sc[256];
    int t = threadIdx.x;
    int base = blockIdx.x * 1024 + t * 4;
    u32 v0 = base + 0 < NSCAN ? in[base + 0] : 0;
    u32 v1 = base + 1 < NSCAN ? in[base + 1] : 0;
    u32 v2 = base + 2 < NSCAN ? in[base + 2] : 0;
    u32 v3 = base + 3 < NSCAN ? in[base + 3] : 0;
    if (base + 0 < NSCAN) deg[base + 0] = rsqrtf((float)max(v0, 1u));
    if (base + 1 < NSCAN) deg[base + 1] = rsqrtf((float)max(v1, 1u));
    if (base + 2 < NSCAN) deg[base + 2] = rsqrtf((float)max(v2, 1u));
    if (base + 3 < NSCAN) deg[base + 3] = rsqrtf((float)max(v3, 1u));
    u32 s = v0 + v1 + v2 + v3;
    sc[t] = s; __syncthreads();
    for (int off = 1; off < 256; off <<= 1) {
        u32 x = (t >= off) ? sc[t - off] : 0; __syncthreads();
        sc[t] += x; __syncthreads();
    }
    u32 excl = sc[t] - s;
    if (base + 0 < NSCAN) out[base + 0] = excl;
    if (base + 1 < NSCAN) out[base + 1] = excl + v0;
    if (base + 2 < NSCAN) out[base + 2] = excl + v0 + v1;
    if (base + 3 < NSCAN) out[base + 3] = excl + v0 + v1 + v2;
    if (t == 255) bsum[blockIdx.x] = sc[255];
}

__global__ __launch_bounds__(512) void k_scan2(u32* __restrict__ bsum) {
    __shared__ u32 sc[512];
    int t = threadIdx.x;
    u32 v = (t < SCAN_BLOCKS) ? bsum[t] : 0;
    sc[t] = v; __syncthreads();
    for (int off = 1; off < 512; off <<= 1) {
        u32 x = (t >= off) ? sc[t - off] : 0; __syncthreads();
        sc[t] += x; __syncthreads();
    }
    if (t < SCAN_BLOCKS) bsum[t] = sc[t] - v;
}

__global__ __launch_bounds__(256) void k_scan3(u32* __restrict__ S, const u32* __restrict__ bsum) {
    int i = blockIdx.x * blockDim.x + threadIdx.x;
    if (i < NSCAN) S[i] = S[i] + bsum[i >> 10];
    if (i == 0) S[NSCAN] = 2u * NPIN + 2u * NNN;
}

// ---------------- CSR placement, atomic-free, XCD-partitioned ----------------
// colPNC packs pin | net<<20 | cell<<40
__global__ __launch_bounds__(256) void k_place_part(
    const int* __restrict__ pin_cell, const int* __restrict__ pin_net,
    const int* __restrict__ nn_src, const int* __restrict__ nn_dst,
    const u32* __restrict__ S,
    const u32* __restrict__ rankNp, const u32* __restrict__ rankC,
    const u32* __restrict__ rankD, const u32* __restrict__ rankS,
    u32* __restrict__ colC, u64* __restrict__ colPNC,
    u32* __restrict__ colS, u32* __restrict__ colD) {
    int part = blockIdx.x & 7;
    int grp = blockIdx.x >> 3;
    int ngrp = gridDim.x >> 3;
    int lo = part * PART_SZ, hi = lo + PART_SZ;
    int stride = ngrp * 256;
    for (int e = grp * 256 + threadIdx.x; e < NPIN; e += stride) {
        int n = pin_net[e], c = pin_cell[e];
        if (n >= lo && n < hi)
            colC[S[n] + rankNp[e]] = (u32)c;
        if (c >= lo && c < hi)
            colPNC[S[NNET + c] + rankC[e] - NPIN] =
                (u64)(u32)e | ((u64)(u32)n << 20) | ((u64)(u32)c << 40);
    }
    for (int i = grp * 256 + threadIdx.x; i < NNN; i += stride) {
        int s = nn_src[i], d = nn_dst[i];
        if (d >= lo && d < hi)
            colS[S[2 * NNET + d] + rankD[i] - 2u * NPIN] = (u32)s;
        if (s >= lo && s < hi)
            colD[S[3 * NNET + s] + rankS[i] - (2u * NPIN + NNN)] = (u32)d;
    }
}

// ---------------- e-MLP fused with cell-sum (union LDS, padded f32 stride) ----------------
__global__ __launch_bounds__(256, 4) void k_emlp_fused(
    const float* __restrict__ pin_feat, const u64* __restrict__ colPNC,
    const float* __restrict__ E1, const float* __restrict__ b1,
    const float* __restrict__ E2, const float* __restrict__ b2,
    const u16* __restrict__ hv, u16* __restrict__ acc) {
    // per-wave union: bf16 transpose buffer (2048B) / f32 products 16 rows x SMW (4160B)
    __shared__ __align__(16) char smraw[4][4352];
    __shared__ u64 smc[4][16];
    int tid = threadIdx.x, lane = tid & 63, w = tid >> 6;
    int l15 = lane & 15, g = (lane >> 4) & 3;
    u16* smT = (u16*)smraw[w];
    float* smF = (float*)smraw[w];
    short8 B1[4];
#pragma unroll
    for (int nt = 0; nt < 4; nt++) {
        short8 f = {0, 0, 0, 0, 0, 0, 0, 0};
        if (lane < 16) {
            int c = nt * 16 + l15;
#pragma unroll
            for (int j = 0; j < 8; j++) f[j] = (short)f2bf(E1[j * 64 + c]);
        }
        B1[nt] = f;
    }
    short8 B2[2][4];
#pragma unroll
    for (int kt = 0; kt < 2; kt++)
#pragma unroll
        for (int nt = 0; nt < 4; nt++) B2[kt][nt] = load_bfrag(E2, kt, nt, lane);
    float bb1[4], bb2[4];
#pragma unroll
    for (int nt = 0; nt < 4; nt++) {
        bb1[nt] = b1[nt * 16 + l15];
        bb2[nt] = b2[nt * 16 + l15];
    }
    int wave = blockIdx.x * 4 + w, nwave = gridDim.x * 4;
    const int ntile = NPIN >> 4;    // 31250 exact
    f32x4 z = {0.f, 0.f, 0.f, 0.f};
    for (int t = wave; t < ntile; t += nwave) {
        int P = t << 4;
        short8 a1 = {0, 0, 0, 0, 0, 0, 0, 0};
        if (lane < 16) {
            u64 v = colPNC[P + lane];
            smc[w][lane] = v;
            u32 p = (u32)(v & 0xFFFFFu);
            const float4* q = (const float4*)(pin_feat + (size_t)p * 8);
            float4 u0 = q[0], u1 = q[1];
            u32 w01 = cvtpk(u0.x, u0.y), w23 = cvtpk(u0.z, u0.w);
            u32 w45 = cvtpk(u1.x, u1.y), w67 = cvtpk(u1.z, u1.w);
            a1[0] = (short)(w01 & 0xffff); a1[1] = (short)(w01 >> 16);
            a1[2] = (short)(w23 & 0xffff); a1[3] = (short)(w23 >> 16);
            a1[4] = (short)(w45 & 0xffff); a1[5] = (short)(w45 >> 16);
            a1[6] = (short)(w67 & 0xffff); a1[7] = (short)(w67 >> 16);
        }
#pragma unroll
        for (int nt = 0; nt < 4; nt++) {
            f32x4 c1 = __builtin_amdgcn_mfma_f32_16x16x32_bf16(a1, B1[nt], z, 0, 0, 0);
#pragma unroll
            for (int r = 0; r < 4; r++) {
                int row = g * 4 + r;
                int col = nt * 16 + l15;
                smT[row * 64 + (col ^ ((row & 7) << 3))] = f2bf_fast(sspf(c1[r] + bb1[nt]));
            }
        }
        short8 a2[2];
#pragma unroll
        for (int kt = 0; kt < 2; kt++) {
            int idx = l15 * 64 + ((kt * 32 + g * 8) ^ ((l15 & 7) << 3));
            a2[kt] = *(const short8*)&smT[idx];
        }
        f32x4 ef[4];
#pragma unroll
        for (int nt = 0; nt < 4; nt++) {
            f32x4 e = __builtin_amdgcn_mfma_f32_16x16x32_bf16(a2[0], B2[0][nt], z, 0, 0, 0);
            e = __builtin_amdgcn_mfma_f32_16x16x32_bf16(a2[1], B2[1][nt], e, 0, 0, 0);
#pragma unroll
            for (int r = 0; r < 4; r++) ef[nt][r] = sspf(e[r] + bb2[nt]);
        }
        // products overwrite the (now dead) transpose buffer; padded stride SMW
#pragma unroll
        for (int r = 0; r < 4; r++) {
            u64 v = smc[w][g * 4 + r];
            u32 net = (u32)((v >> 20) & 0xFFFFFu);
#pragma unroll
            for (int nt = 0; nt < 4; nt++) {
                float h = bf2f(hv[(size_t)net * 64 + nt * 16 + l15]);
                smF[(g * 4 + r) * SMW + nt * 16 + l15] = ef[nt][r] * h;
            }
        }
        // wave-uniform segmented reduction over the 16 rows; lane = col
        float a = smF[lane];
        u32 prev = (u32)(smc[w][0] >> 40);
        int r0 = 0;
#pragma unroll
        for (int r = 1; r < 16; r++) {
            u32 cr = (u32)(smc[w][r] >> 40);
            if (cr != prev) {
                if (r0 > 0) {   // interior segment: exclusive to this tile
                    acc[(size_t)prev * 64 + lane] = f2bf_fast(a);
                } else {        // may extend into previous tile
                    float ap = __shfl_xor(a, 1, 64);
                    if (!(lane & 1)) pk_add(acc + (size_t)prev * 64 + lane, cvtpk(a, ap));
                }
                a = smF[r * SMW + lane];
                prev = cr;
                r0 = r;
            } else {
                a += smF[r * SMW + lane];
            }
        }
        {   // final segment: may extend into next tile
            float ap = __shfl_xor(a, 1, 64);
            if (!(lane & 1)) pk_add(acc + (size_t)prev * 64 + lane, cvtpk(a, ap));
        }
    }
}

// ---------------- hv = h_net @ cf_node_w + b ----------------
__global__ __launch_bounds__(256, 4) void k_mm64hv(
    const u16* __restrict__ in, const float* __restrict__ W,
    const float* __restrict__ b, u16* __restrict__ out, int n) {
    int tid = threadIdx.x, lane = tid & 63, w = tid >> 6;
    int l15 = lane & 15, g = (lane >> 4) & 3;
    short8 Bf[2][4];
    float bias[4];
#pragma unroll
    for (int kt = 0; kt < 2; kt++)
#pragma unroll
        for (int nt = 0; nt < 4; nt++) Bf[kt][nt] = load_bfrag(W, kt, nt, lane);
#pragma unroll
    for (int nt = 0; nt < 4; nt++) bias[nt] = b[nt * 16 + l15];
    int wave = blockIdx.x * 4 + w, nwave = gridDim.x * 4;
    int ntile = n >> 4;
    f32x4 z = {0.f, 0.f, 0.f, 0.f};
    for (int t = wave; t < ntile; t += nwave) {
        int R = t << 4;
        const u16* rb = in + (size_t)(R + l15) * 64;
        short8 a0 = *(const short8*)(rb + g * 8);
        short8 a1 = *(const short8*)(rb + 32 + g * 8);
#pragma unroll
        for (int nt = 0; nt < 4; nt++) {
            f32x4 acc = __builtin_amdgcn_mfma_f32_16x16x32_bf16(a0, Bf[0][nt], z, 0, 0, 0);
            acc = __builtin_amdgcn_mfma_f32_16x16x32_bf16(a1, Bf[1][nt], acc, 0, 0, 0);
#pragma unroll
            for (int r = 0; r < 4; r++) {
                float v = acc[r] + bias[nt];
                float vp = __shfl_xor(v, 1, 64);
                if (!(lane & 1))
                    *(u32*)(out + (size_t)(R + g * 4 + r) * 64 + nt * 16 + l15) = cvtpk(v, vp);
            }
        }
    }
}

// ---------------- gather-sum: accP[n] = sum rC[c]*h_cell[c] ----------------
__global__ __launch_bounds__(256) void k_gatherP(
    const u32* __restrict__ S, const u32* __restrict__ colC,
    const u16* __restrict__ h_cell, const float* __restrict__ rCv,
    u16* __restrict__ accP) {
    int l32 = threadIdx.x & 31, off2 = l32 * 2;
    int slot = blockIdx.x * 8 + (threadIdx.x >> 5), ns = gridDim.x * 8;
    for (int n = slot; n < NNET; n += ns) {
        u32 b0 = S[n], b1 = S[n + 1];
        float fa = 0.f, fb = 0.f, ga = 0.f, gb = 0.f;
        u32 k = b0;
        for (; k + 1 < b1; k += 2) {
            u32 c0 = colC[k], c1 = colC[k + 1];
            float r0 = rCv[c0], r1 = rCv[c1];
            u32 h0 = *(const u32*)(h_cell + (size_t)c0 * 64 + off2);
            u32 h1 = *(const u32*)(h_cell + (size_t)c1 * 64 + off2);
            fa = fmaf(plo(h0), r0, fa); fb = fmaf(phi(h0), r0, fb);
            ga = fmaf(plo(h1), r1, ga); gb = fmaf(phi(h1), r1, gb);
        }
        if (k < b1) {
            u32 c0 = colC[k];
            float r0 = rCv[c0];
            u32 h0 = *(const u32*)(h_cell + (size_t)c0 * 64 + off2);
            fa = fmaf(plo(h0), r0, fa); fb = fmaf(phi(h0), r0, fb);
        }
        *(u32*)(accP + (size_t)n * 64 + off2) = cvtpk(fa + ga, fb + gb);
    }
}

// ---------------- gather-sum for both nn relations ----------------
__global__ __launch_bounds__(256) void k_gatherFS(
    const u32* __restrict__ S, const u32* __restrict__ colS, const u32* __restrict__ colD,
    const u16* __restrict__ h_net, const float* __restrict__ rDv, const float* __restrict__ rSv,
    u16* __restrict__ accF, u16* __restrict__ accS) {
    int l32 = threadIdx.x & 31, off2 = l32 * 2;
    int slot = blockIdx.x * 8 + (threadIdx.x >> 5), ns = gridDim.x * 8;
    for (int r = slot; r < 2 * NNET; r += ns) {
        if (r < NNET) {
            int d = r;
            u32 b0 = S[2 * NNET + d] - 2u * NPIN, b1 = S[2 * NNET + d + 1] - 2u * NPIN;
            float fa = 0.f, fb = 0.f, ga = 0.f, gb = 0.f;
            u32 k = b0;
            for (; k + 1 < b1; k += 2) {
                u32 s0 = colS[k], s1 = colS[k + 1];
                float c0 = rSv[s0], c1 = rSv[s1];
                u32 h0 = *(const u32*)(h_net + (size_t)s0 * 64 + off2);
                u32 h1 = *(const u32*)(h_net + (size_t)s1 * 64 + off2);
                fa = fmaf(plo(h0), c0, fa); fb = fmaf(phi(h0), c0, fb);
                ga = fmaf(plo(h1), c1, ga); gb = fmaf(phi(h1), c1, gb);
            }
            if (k < b1) {
                u32 s0 = colS[k];
                float c0 = rSv[s0];
                u32 h0 = *(const u32*)(h_net + (size_t)s0 * 64 + off2);
                fa = fmaf(plo(h0), c0, fa); fb = fmaf(phi(h0), c0, fb);
            }
            *(u32*)(accF + (size_t)d * 64 + off2) = cvtpk(fa + ga, fb + gb);
        } else {
            int s = r - NNET;
            u32 b0 = S[3 * NNET + s] - (2u * NPIN + NNN), b1 = S[3 * NNET + s + 1] - (2u * NPIN + NNN);
            float fa = 0.f, fb = 0.f, ga = 0.f, gb = 0.f;
            u32 k = b0;
            for (; k + 1 < b1; k += 2) {
                u32 d0 = colD[k], d1 = colD[k + 1];
                float c0 = rDv[d0], c1 = rDv[d1];
                u32 h0 = *(const u32*)(h_net + (size_t)d0 * 64 + off2);
                u32 h1 = *(const u32*)(h_net + (size_t)d1 * 64 + off2);
                fa = fmaf(plo(h0), c0, fa); fb = fmaf(phi(h0), c0, fb);
                ga = fmaf(plo(h1), c1, ga); gb = fmaf(phi(h1), c1, gb);
            }
            if (k < b1) {
                u32 d0 = colD[k];
                float c0 = rDv[d0];
                u32 h0 = *(const u32*)(h_net + (size_t)d0 * 64 + off2);
                fa = fmaf(plo(h0), c0, fa); fb = fmaf(phi(h0), c0, fb);
            }
            *(u32*)(accS + (size_t)s * 64 + off2) = cvtpk(fa + ga, fb + gb);
        }
    }
}

// ---------------- 3-relation combine + row scales + fused ntab dots ----------------
__global__ __launch_bounds__(256, 2) void k_combine3(
    const u16* __restrict__ A0, const float* __restrict__ W0, const float* __restrict__ b0,
    const u16* __restrict__ A1, const float* __restrict__ W1, const float* __restrict__ b1,
    const u16* __restrict__ A2, const float* __restrict__ W2, const float* __restrict__ b2,
    const float* __restrict__ sc0, const float* __restrict__ sc1, const float* __restrict__ sc2,
    const float* __restrict__ ndw, const float* __restrict__ naw,
    const float* __restrict__ pdw, const float* __restrict__ paw,
    float* __restrict__ ntab, int n) {
    int tid = threadIdx.x, lane = tid & 63, w = tid >> 6;
    int l15 = lane & 15, g = (lane >> 4) & 3;
    const float* Ws[3] = {W0, W1, W2};
    const float* bs[3] = {b0, b1, b2};
    const u16* As[3] = {A0, A1, A2};
    short8 Bf[3][2][4];
    float bias[3][4];
#pragma unroll
    for (int rel = 0; rel < 3; rel++) {
#pragma unroll
        for (int kt = 0; kt < 2; kt++)
#pragma unroll
            for (int nt = 0; nt < 4; nt++) Bf[rel][kt][nt] = load_bfrag(Ws[rel], kt, nt, lane);
#pragma unroll
        for (int nt = 0; nt < 4; nt++) bias[rel][nt] = bs[rel][nt * 16 + l15];
    }
    float wt[6][4];
#pragma unroll
    for (int nt = 0; nt < 4; nt++) {
        int c = nt * 16 + l15;
        wt[0][nt] = ndw[c];      wt[1][nt] = naw[c];
        wt[2][nt] = ndw[64 + c]; wt[3][nt] = naw[64 + c];
        wt[4][nt] = pdw[c];      wt[5][nt] = paw[c];
    }
    int wave = blockIdx.x * 4 + w, nwave = gridDim.x * 4;
    int ntile = n >> 4;
    f32x4 z = {0.f, 0.f, 0.f, 0.f};
    for (int t = wave; t < ntile; t += nwave) {
        int R = t << 4;
        int rowA = R + l15;
        float s0a[4], s1a[4], s2a[4];
        *(float4*)s0a = *(const float4*)(sc0 + R + g * 4);
        *(float4*)s1a = *(const float4*)(sc1 + R + g * 4);
        *(float4*)s2a = *(const float4*)(sc2 + R + g * 4);
        f32x4 res[4];
#pragma unroll
        for (int rel = 0; rel < 3; rel++) {
            const u16* rb = As[rel] + (size_t)rowA * 64;
            short8 a0 = *(const short8*)(rb + g * 8);
            short8 a1 = *(const short8*)(rb + 32 + g * 8);
            const float* sa = (rel == 0) ? s0a : (rel == 1) ? s1a : s2a;
#pragma unroll
            for (int nt = 0; nt < 4; nt++) {
                f32x4 acc = __builtin_amdgcn_mfma_f32_16x16x32_bf16(a0, Bf[rel][0][nt], z, 0, 0, 0);
                acc = __builtin_amdgcn_mfma_f32_16x16x32_bf16(a1, Bf[rel][1][nt], acc, 0, 0, 0);
                if (rel == 0) {
#pragma unroll
                    for (int r = 0; r < 4; r++) res[nt][r] = sa[r] * acc[r] + bias[0][nt];
                } else {
#pragma unroll
                    for (int r = 0; r < 4; r++)
                        res[nt][r] = fmaxf(res[nt][r], sa[r] * acc[r] + bias[rel][nt]);
                }
            }
        }
#pragma unroll
        for (int r = 0; r < 4; r++) {
            float a0 = 0.f, a1 = 0.f, a2 = 0.f, a3 = 0.f, a4 = 0.f, a5 = 0.f;
#pragma unroll
            for (int nt = 0; nt < 4; nt++) {
                float v = res[nt][r];
                a0 = fmaf(v, wt[0][nt], a0);
                a1 = fmaf(v, wt[1][nt], a1);
                a2 = fmaf(v, wt[2][nt], a2);
                a3 = fmaf(v, wt[3][nt], a3);
                a4 = fmaf(v, wt[4][nt], a4);
                a5 = fmaf(v, wt[5][nt], a5);
            }
#pragma unroll
            for (int off = 1; off < 16; off <<= 1) {
                a0 += __shfl_xor(a0, off, 64);
                a1 += __shfl_xor(a1, off, 64);
                a2 += __shfl_xor(a2, off, 64);
                a3 += __shfl_xor(a3, off, 64);
                a4 += __shfl_xor(a4, off, 64);
                a5 += __shfl_xor(a5, off, 64);
            }
            if (l15 == 0) {
                float* tp = ntab + (size_t)(R + g * 4 + r) * 8;
                *(float2*)tp = float2{a0, a1};
                *(float2*)(tp + 2) = float2{a2, a3};
                *(float2*)(tp + 4) = float2{a4, a5};
            }
        }
    }
}

// ---------------- cell out-layer: ssp(acc @ W + b) fused with ctab dots ----------------
__global__ __launch_bounds__(256, 3) void k_mm64c(
    const u16* __restrict__ in, const float* __restrict__ W, const float* __restrict__ b,
    const float* __restrict__ pdw, const float* __restrict__ paw,
    float* __restrict__ ctab, int n) {
    int tid = threadIdx.x, lane = tid & 63, w = tid >> 6;
    int l15 = lane & 15, g = (lane >> 4) & 3;
    short8 Bf[2][4];
    float bias[4], wdv[4], wav[4];
#pragma unroll
    for (int kt = 0; kt < 2; kt++)
#pragma unroll
        for (int nt = 0; nt < 4; nt++) Bf[kt][nt] = load_bfrag(W, kt, nt, lane);
#pragma unroll
    for (int nt = 0; nt < 4; nt++) {
        int c = nt * 16 + l15;
        bias[nt] = b[c];
        wdv[nt] = pdw[72 + c];
        wav[nt] = paw[72 + c];
    }
    int wave = blockIdx.x * 4 + w, nwave = gridDim.x * 4;
    int ntile = n >> 4;
    f32x4 z = {0.f, 0.f, 0.f, 0.f};
    for (int t = wave; t < ntile; t += nwave) {
        int R = t << 4;
        const u16* rb = in + (size_t)(R + l15) * 64;
        short8 a0 = *(const short8*)(rb + g * 8);
        short8 a1 = *(const short8*)(rb + 32 + g * 8);
        float sd[4] = {0.f, 0.f, 0.f, 0.f}, sa[4] = {0.f, 0.f, 0.f, 0.f};
#pragma unroll
        for (int nt = 0; nt < 4; nt++) {
            f32x4 acc = __builtin_amdgcn_mfma_f32_16x16x32_bf16(a0, Bf[0][nt], z, 0, 0, 0);
            acc = __builtin_amdgcn_mfma_f32_16x16x32_bf16(a1, Bf[1][nt], acc, 0, 0, 0);
#pragma unroll
            for (int r = 0; r < 4; r++) {
                float v = sspf(acc[r] + bias[nt]);
                sd[r] = fmaf(v, wdv[nt], sd[r]);
                sa[r] = fmaf(v, wav[nt], sa[r]);
            }
        }
#pragma unroll
        for (int r = 0; r < 4; r++) {
            float d = sd[r], a = sa[r];
#pragma unroll
            for (int off = 1; off < 16; off <<= 1) {
                d += __shfl_xor(d, off, 64);
                a += __shfl_xor(a, off, 64);
            }
            if (l15 == 0)
                *(float2*)(ctab + (size_t)(R + g * 4 + r) * 2) = float2{d, a};
        }
    }
}

// ---------------- fused pair + pin readout ----------------
__global__ __launch_bounds__(256) void k_readout(
    const int* __restrict__ pairs,
    const float* __restrict__ pin_feat,
    const int* __restrict__ pin_net, const int* __restrict__ pin_cell,
    const float* __restrict__ ntab, const float* __restrict__ ctab,
    const float* __restrict__ plw, const float* __restrict__ plb,
    const float* __restrict__ pdw, const float* __restrict__ paw,
    const float* __restrict__ nbd, const float* __restrict__ nba,
    const float* __restrict__ pbd, const float* __restrict__ pba,
    float* __restrict__ out) {
    int i = blockIdx.x * blockDim.x + threadIdx.x;
    if (i < NPAIR) {
        int p0 = pairs[2 * i], p1 = pairs[2 * i + 1];
        float2 x0 = *(const float2*)(ntab + (size_t)p0 * 8);
        float2 x1 = *(const float2*)(ntab + (size_t)p1 * 8 + 2);
        out[i] = softplusf(x0.x + x1.x + nbd[0]);
        out[NPAIR + i] = x0.y + x1.y + nba[0];
    } else if (i < NPAIR + NPIN) {
        int p = i - NPAIR;
        int n = pin_net[p], c = pin_cell[p];
        float2 ns = *(const float2*)(ntab + (size_t)n * 8 + 4);
        float2 cs = *(const float2*)(ctab + (size_t)c * 2);
        float pf[8];
        *(float4*)pf = *(const float4*)(pin_feat + (size_t)p * 8);
        *(float4*)(pf + 4) = *(const float4*)(pin_feat + (size_t)p * 8 + 4);
        float sd = ns.x + cs.x + pbd[0];
        float sa = ns.y + cs.y + pba[0];
#pragma unroll
        for (int j = 0; j < 8; j++) {
            float a = plb[j];
#pragma unroll
            for (int k = 0; k < 8; k++) a = fmaf(pf[k], plw[k * 8 + j], a);
            float hp = ftanh(a);
            sd = fmaf(hp, pdw[64 + j], sd);
            sa = fmaf(hp, paw[64 + j], sa);
        }
        out[2 * NPAIR + p] = softplusf(sd);
        out[2 * NPAIR + NPIN + p] = sa;
    }
}

extern "C" void kernel_launch(void* const* d_in, const int* in_sizes, int n_in,
                              void* d_out, int out_size, void* d_ws, size_t ws_size,
                              hipStream_t stream) {
    const float* cell_feat = (const float*)d_in[0];
    const float* net_feat  = (const float*)d_in[1];
    const float* pin_feat  = (const float*)d_in[2];
    const float* cell_lin_w = (const float*)d_in[3];
    const float* cell_lin_b = (const float*)d_in[4];
    const float* net_lin_w  = (const float*)d_in[5];
    const float* net_lin_b  = (const float*)d_in[6];
    const float* pin_lin_w  = (const float*)d_in[7];
    const float* pin_lin_b  = (const float*)d_in[8];
    const float* pins_w   = (const float*)d_in[9];
    const float* pins_b   = (const float*)d_in[10];
    const float* father_w = (const float*)d_in[11];
    const float* father_b = (const float*)d_in[12];
    const float* son_w    = (const float*)d_in[13];
    const float* son_b    = (const float*)d_in[14];
    const float* cf_node_w = (const float*)d_in[15];
    const float* cf_node_b = (const float*)d_in[16];
    const float* cf_e1_w  = (const float*)d_in[17];
    const float* cf_e1_b  = (const float*)d_in[18];
    const float* cf_e2_w  = (const float*)d_in[19];
    const float* cf_e2_b  = (const float*)d_in[20];
    const float* cf_out_w = (const float*)d_in[21];
    const float* cf_out_b = (const float*)d_in[22];
    const float* net_dis_w   = (const float*)d_in[23];
    const float* net_dis_b   = (const float*)d_in[24];
    const float* net_angle_w = (const float*)d_in[25];
    const float* net_angle_b = (const float*)d_in[26];
    const float* pin_dis_w   = (const float*)d_in[27];
    const float* pin_dis_b   = (const float*)d_in[28];
    const float* pin_angle_w = (const float*)d_in[29];
    const float* pin_angle_b = (const float*)d_in[30];
    const int* pin_net = (const int*)d_in[31];
    const int* pin_cell = (const int*)d_in[32];
    const int* nn_src = (const int*)d_in[33];
    const int* nn_dst = (const int*)d_in[34];
    const int* pairs = (const int*)d_in[35];

    u16* ws16 = (u16*)d_ws;
    const size_t SZ = (size_t)NNET * 64;
    // u16 slots: 0 h_cell | 1 h_net | 2 accP | 3 accF | 4 accS | 5 acc_cell | 6 hv
    u16* h_cell   = ws16;
    u16* h_net    = ws16 + SZ;
    u16* accP     = ws16 + 2 * SZ;
    u16* accF     = ws16 + 3 * SZ;
    u16* accS     = ws16 + 4 * SZ;
    u16* acc_cell = ws16 + 5 * SZ;
    u16* hv       = ws16 + 6 * SZ;
    u32* tail = (u32*)(ws16 + 7 * SZ);
    u32* cnt    = tail;                        // 400000
    u32* Sarr   = cnt + NSCAN;                 // 400002
    u32* rankNp = Sarr + NSCAN + 2;            // 500000
    u32* rankC  = rankNp + NPIN;               // 500000
    u32* rankD  = rankC + NPIN;                // 200000
    u32* rankS  = rankD + NNN;                 // 200000
    u32* colC   = rankS + NNN;                 // 500000
    u32* colS   = colC + NPIN;                 // 200000
    u32* colD   = colS + NNN;                  // 200000
    u64* colPNC = (u64*)(colD + NNN);          // 500000 u64
    u32* bsum   = (u32*)(colPNC + NPIN);       // 512
    float* deg  = (float*)(bsum + 512);        // NSCAN: [rNp|rC|rD|rS]
    float* rNp = deg;
    float* rC  = deg + NNET;
    float* rD  = deg + 2 * NNET;
    float* rS  = deg + 3 * NNET;
    float* ntab = deg + NSCAN;                 // NNET*8
    float* ctab = ntab + (size_t)NNET * 8;     // NCELL*2

    hipMemsetAsync(cnt, 0, NSCAN * sizeof(u32), stream);
    hipMemsetAsync(acc_cell, 0, SZ * sizeof(u16), stream);   // boundary-atomic accumulator

    k_degrees<<<(NPIN + 255) / 256, 256, 0, stream>>>(
        pin_cell, pin_net, nn_src, nn_dst, cnt, rankNp, rankC, rankD, rankS);
    k_lin16_all<<<2048, 256, 0, stream>>>(cell_feat, net_feat,
                                          cell_lin_w, cell_lin_b, net_lin_w, net_lin_b,
                                          h_cell, h_net);

    k_scan1<<<SCAN_BLOCKS, 256, 0, stream>>>(cnt, Sarr, bsum, deg);
    k_scan2<<<1, 512, 0, stream>>>(bsum);
    k_scan3<<<(NSCAN + 255) / 256, 256, 0, stream>>>(Sarr, bsum);
    k_place_part<<<2048, 256, 0, stream>>>(pin_cell, pin_net, nn_src, nn_dst,
                                           Sarr, rankNp, rankC, rankD, rankS,
                                           colC, colPNC, colS, colD);

    k_mm64hv<<<1024, 256, 0, stream>>>(h_net, cf_node_w, cf_node_b, hv, NNET);
    k_gatherP<<<2048, 256, 0, stream>>>(Sarr, colC, h_cell, rC, accP);
    k_gatherFS<<<2048, 256, 0, stream>>>(Sarr, colS, colD, h_net, rD, rS, accF, accS);

    // e-MLP + cell-sum fused (no etab round-trip)
    k_emlp_fused<<<2048, 256, 0, stream>>>(pin_feat, colPNC,
                                           cf_e1_w, cf_e1_b, cf_e2_w, cf_e2_b,
                                           hv, acc_cell);

    k_combine3<<<512, 256, 0, stream>>>(accP, pins_w, pins_b,
                                        accF, father_w, father_b,
                                        accS, son_w, son_b,
                                        rNp, rD, rS,
                                        net_dis_w, net_angle_w, pin_dis_w, pin_angle_w,
                                        ntab, NNET);

    k_mm64c<<<512, 256, 0, stream>>>(acc_cell, cf_out_w, cf_out_b,
                                     pin_dis_w, pin_angle_w, ctab, NCELL);

    float* out = (float*)d_out;
    k_readout<<<(NPAIR + NPIN + 255) / 256, 256, 0, stream>>>(
        pairs, pin_feat, pin_net, pin_cell, ntab, ctab,
        pin_lin_w, pin_lin_b, pin_dis_w, pin_angle_w,
        net_dis_b, net_angle_b, pin_dis_b, pin_angle_b, out);
}